// Round 5
// baseline (586.910 us; speedup 1.0000x reference)
//
#include <hip/hip_runtime.h>
#include <math.h>

#define F_IN 128
#define HID  64
#define NH   4
#define DD   16
#define CC   16
#define CSTE 1e-5f

typedef _Float16 half4 __attribute__((ext_vector_type(4)));
typedef _Float16 half8 __attribute__((ext_vector_type(8)));

// ---------------- gamma precompute (16 floats) ----------------
__global__ void gamma_kernel(const float* __restrict__ hopwise,
                             const float* __restrict__ temp,
                             float* __restrict__ gam) {
    if (threadIdx.x == 0 && blockIdx.x == 0) {
        for (int h = 0; h < NH; ++h) gam[h * 4 + 0] = temp[h * 4 + 0]; // hop0: raw temp
        for (int hop = 1; hop <= 3; ++hop) {
            float m = -1e30f;
            for (int h = 0; h < NH; ++h) m = fmaxf(m, temp[h * 4 + hop]);
            float e[NH], s = 0.f;
            for (int h = 0; h < NH; ++h) { e[h] = expf(temp[h * 4 + hop] - m); s += e[h]; }
            for (int h = 0; h < NH; ++h) gam[h * 4 + hop] = hopwise[hop] * e[h] / s;
        }
    }
}

// ---------------- CSR build ----------------
__global__ void count_kernel(const int* __restrict__ ei, int* __restrict__ deg, int E) {
    int e = blockIdx.x * blockDim.x + threadIdx.x;
    if (e < E) atomicAdd(&deg[ei[E + e]], 1);   // dst = ei[1][e]
}

__global__ void scan_kernel(const int* __restrict__ deg, int* __restrict__ offsets, int N) {
    __shared__ int wsum[16], woff[16];
    __shared__ int carry;
    int lane = threadIdx.x & 63, w = threadIdx.x >> 6;
    if (threadIdx.x == 0) carry = 0;
    __syncthreads();
    for (int base = 0; base < N; base += 4096) {
        int i0 = base + (int)threadIdx.x * 4;
        int d0 = (i0 + 0 < N) ? deg[i0 + 0] : 0;
        int d1 = (i0 + 1 < N) ? deg[i0 + 1] : 0;
        int d2 = (i0 + 2 < N) ? deg[i0 + 2] : 0;
        int d3 = (i0 + 3 < N) ? deg[i0 + 3] : 0;
        int tsum = d0 + d1 + d2 + d3;
        int incl = tsum;
        #pragma unroll
        for (int m = 1; m < 64; m <<= 1) {
            int t = __shfl_up(incl, m, 64);
            if (lane >= m) incl += t;
        }
        if (lane == 63) wsum[w] = incl;
        __syncthreads();
        if (threadIdx.x == 0) {
            int r = carry;
            for (int k = 0; k < 16; ++k) { int t = wsum[k]; woff[k] = r; r += t; }
            carry = r;
        }
        __syncthreads();
        int excl = woff[w] + incl - tsum;
        if (i0 + 0 < N) offsets[i0 + 0] = excl;
        if (i0 + 1 < N) offsets[i0 + 1] = excl + d0;
        if (i0 + 2 < N) offsets[i0 + 2] = excl + d0 + d1;
        if (i0 + 3 < N) offsets[i0 + 3] = excl + d0 + d1 + d2;
        __syncthreads();
    }
    if (threadIdx.x == 0) offsets[N] = carry;
}

__global__ void scatter_kernel(const int* __restrict__ ei, const int* __restrict__ offsets,
                               int* __restrict__ cursor, int* __restrict__ csr, int E) {
    int e = blockIdx.x * blockDim.x + threadIdx.x;
    if (e < E) {
        int src = ei[e];
        int dst = ei[E + e];
        int pos = atomicAdd(&cursor[dst], 1);
        csr[offsets[dst] + pos] = src;
    }
}

// ---------------- QKV + hop-0 hidden (32 nodes/block, 8 nodes/thread) ----------------
__global__ __launch_bounds__(256) void qkv_kernel(
    const float* __restrict__ x,
    const float* __restrict__ Wi, const float* __restrict__ bi,
    const float* __restrict__ Wq, const float* __restrict__ bq,
    const float* __restrict__ Wk, const float* __restrict__ bk,
    const float* __restrict__ Wv, const float* __restrict__ bv,
    const float* __restrict__ gam,
    float* __restrict__ Q, _Float16* __restrict__ K0, float* __restrict__ V,
    float* __restrict__ hidden, int N)
{
    __shared__ float xs[32][F_IN];
    __shared__ float hs[32][HID];
    int t = threadIdx.x;
    int base = blockIdx.x * 32;
    {
        const float4* xg = (const float4*)(x + (size_t)base * F_IN);
        float4* xls = (float4*)&xs[0][0];
        int maxf = min(32, N - base) * (F_IN / 4);
        #pragma unroll
        for (int k = 0; k < 4; ++k) {
            int f = t + k * 256;
            if (f < maxf) xls[f] = xg[f];
        }
    }
    __syncthreads();
    int col = t & 63, w = t >> 6;
    float acc[8];
    #pragma unroll
    for (int i = 0; i < 8; ++i) acc[i] = bi[col];
    for (int j0 = 0; j0 < F_IN; j0 += 4) {
        float w0 = Wi[(j0 + 0) * HID + col];
        float w1 = Wi[(j0 + 1) * HID + col];
        float w2 = Wi[(j0 + 2) * HID + col];
        float w3 = Wi[(j0 + 3) * HID + col];
        #pragma unroll
        for (int i = 0; i < 8; ++i) {
            float4 xv = *(const float4*)&xs[w + 4 * i][j0];
            acc[i] += w0 * xv.x + w1 * xv.y + w2 * xv.z + w3 * xv.w;
        }
    }
    #pragma unroll
    for (int i = 0; i < 8; ++i) hs[w + 4 * i][col] = fmaxf(acc[i], 0.f);
    __syncthreads();
    float aq[8], ak[8], av[8];
    #pragma unroll
    for (int i = 0; i < 8; ++i) { aq[i] = bq[col]; ak[i] = bk[col]; av[i] = bv[col]; }
    for (int j0 = 0; j0 < HID; j0 += 4) {
        float q0 = Wq[(j0 + 0) * HID + col], k0 = Wk[(j0 + 0) * HID + col], v0 = Wv[(j0 + 0) * HID + col];
        float q1 = Wq[(j0 + 1) * HID + col], k1 = Wk[(j0 + 1) * HID + col], v1 = Wv[(j0 + 1) * HID + col];
        float q2 = Wq[(j0 + 2) * HID + col], k2 = Wk[(j0 + 2) * HID + col], v2 = Wv[(j0 + 2) * HID + col];
        float q3 = Wq[(j0 + 3) * HID + col], k3 = Wk[(j0 + 3) * HID + col], v3 = Wv[(j0 + 3) * HID + col];
        #pragma unroll
        for (int i = 0; i < 8; ++i) {
            float4 hv = *(const float4*)&hs[w + 4 * i][j0];
            aq[i] += q0 * hv.x + q1 * hv.y + q2 * hv.z + q3 * hv.w;
            ak[i] += k0 * hv.x + k1 * hv.y + k2 * hv.z + k3 * hv.w;
            av[i] += v0 * hv.x + v1 * hv.y + v2 * hv.z + v3 * hv.w;
        }
    }
    int h = col >> 4;
    float g0 = gam[h * 4 + 0];
    #pragma unroll
    for (int i = 0; i < 8; ++i) {
        int node = base + w + 4 * i;
        if (node >= N) continue;
        float qv = (aq[i] > 0.f) ? (1.f + aq[i]) : expf(aq[i]);
        float kv = (ak[i] > 0.f) ? (1.f + ak[i]) : expf(ak[i]);
        Q [(size_t)node * 64 + col] = qv;
        K0[(size_t)node * 64 + col] = (_Float16)kv;
        V [(size_t)node * 64 + col] = av[i];
        hidden[(size_t)node * 64 + col] = av[i] * g0;
    }
}

// M layout (fast path): per node 1024 halfs = [chalf(2)][lane(64)][j(8)],
// slot j on lane (h*16+p) holds M[h][d=p][col = chalf*8 + ((p&7)^j)].

// ---------------- fast hop 1: all heads, M1 = A (K ⊗ V), K1 = A K0, hidden += ----------------
__global__ __launch_bounds__(256) void hop1_all(
    const float* __restrict__ Q, const _Float16* __restrict__ K0, const float* __restrict__ V,
    const int* __restrict__ offsets, const int* __restrict__ csr,
    const float* __restrict__ gam,
    _Float16* __restrict__ M1, _Float16* __restrict__ K1, float* __restrict__ hidden, int N)
{
    int lane = threadIdx.x & 63;
    int node = blockIdx.x * 4 + (threadIdx.x >> 6);
    if (node >= N) return;
    int p = lane & 15;      // d within head
    int hb = lane & 48;     // h*16
    float u[16];
    #pragma unroll
    for (int j = 0; j < 16; ++j) u[j] = 0.f;
    float kacc = 0.f;
    int beg = offsets[node], end = offsets[node + 1];
    int t = beg;
    for (; t + 1 < end; t += 2) {
        int s0 = csr[t], s1 = csr[t + 1];
        float v0 = V[(size_t)s0 * 64 + lane];
        float v1 = V[(size_t)s1 * 64 + lane];
        float k0 = (float)K0[(size_t)s0 * 64 + lane];
        float k1 = (float)K0[(size_t)s1 * 64 + lane];
        kacc += k0 + k1;
        #pragma unroll
        for (int j = 0; j < 16; ++j) {
            int col = (j & 8) + ((p & 7) ^ (j & 7));
            u[j] += k0 * __shfl(v0, hb + col, 64) + k1 * __shfl(v1, hb + col, 64);
        }
    }
    for (; t < end; ++t) {
        int s = csr[t];
        float vv = V[(size_t)s * 64 + lane];
        float kk = (float)K0[(size_t)s * 64 + lane];
        kacc += kk;
        #pragma unroll
        for (int j = 0; j < 16; ++j) {
            int col = (j & 8) + ((p & 7) ^ (j & 7));
            u[j] += kk * __shfl(vv, hb + col, 64);
        }
    }
    // store M1 in split layout
    half8 s0h, s1h;
    #pragma unroll
    for (int j = 0; j < 8; ++j) { s0h[j] = (_Float16)u[j]; s1h[j] = (_Float16)u[8 + j]; }
    *(half8*)(M1 + (size_t)node * 1024 +       lane * 8) = s0h;
    *(half8*)(M1 + (size_t)node * 1024 + 512 + lane * 8) = s1h;
    K1[(size_t)node * 64 + lane] = (_Float16)kacc;
    // epilogue
    float qd = Q[(size_t)node * 64 + lane];
    #pragma unroll
    for (int j = 0; j < 16; ++j) u[j] *= qd;
    #pragma unroll
    for (int b = 0; b < 16; b += 8) {
        u[b + 0] += __shfl_xor(u[b + 1], 1, 64);
        u[b + 2] += __shfl_xor(u[b + 3], 1, 64);
        u[b + 4] += __shfl_xor(u[b + 5], 1, 64);
        u[b + 6] += __shfl_xor(u[b + 7], 1, 64);
        u[b + 0] += __shfl_xor(u[b + 2], 2, 64);
        u[b + 4] += __shfl_xor(u[b + 6], 2, 64);
        u[b + 0] += __shfl_xor(u[b + 4], 4, 64);
        u[b + 0] += __shfl_xor(u[b + 0], 8, 64);
    }
    float kq = qd * kacc;
    kq += __shfl_xor(kq, 1, 64);
    kq += __shfl_xor(kq, 2, 64);
    kq += __shfl_xor(kq, 4, 64);
    kq += __shfl_xor(kq, 8, 64);
    float g = gam[(lane >> 4) * 4 + 1] / (kq + CSTE);
    hidden[(size_t)node * 64 + lane] += g * ((lane & 8) ? u[8] : u[0]);
}

// ---------------- fast hops 2/3: one c-half per dispatch ----------------
template<bool FIRST>
__global__ __launch_bounds__(256) void hop23_pass(
    const float* __restrict__ Q, const _Float16* __restrict__ Mprev,
    const _Float16* __restrict__ Kprev,
    const int* __restrict__ offsets, const int* __restrict__ csr,
    const float* __restrict__ gam,
    _Float16* __restrict__ Mnext, _Float16* __restrict__ Knext,
    float* __restrict__ den_out, const float* __restrict__ den_in,
    float* __restrict__ hidden, int N, int hop, int chalf)
{
    int lane = threadIdx.x & 63;
    int node = blockIdx.x * 4 + (threadIdx.x >> 6);
    if (node >= N) return;
    int p = lane & 15, h = lane >> 4;
    const _Float16* Mb = Mprev + (size_t)chalf * 512 + lane * 8;
    float u[8];
    #pragma unroll
    for (int j = 0; j < 8; ++j) u[j] = 0.f;
    float kacc = 0.f;
    int beg = offsets[node], end = offsets[node + 1];
    int t = beg;
    for (; t + 3 < end; t += 4) {
        int s0 = csr[t], s1 = csr[t + 1], s2 = csr[t + 2], s3 = csr[t + 3];
        half8 a = *(const half8*)(Mb + (size_t)s0 * 1024);
        half8 b = *(const half8*)(Mb + (size_t)s1 * 1024);
        half8 c = *(const half8*)(Mb + (size_t)s2 * 1024);
        half8 d = *(const half8*)(Mb + (size_t)s3 * 1024);
        if (FIRST) {
            kacc += ((float)Kprev[(size_t)s0 * 64 + lane] + (float)Kprev[(size_t)s1 * 64 + lane])
                  + ((float)Kprev[(size_t)s2 * 64 + lane] + (float)Kprev[(size_t)s3 * 64 + lane]);
        }
        #pragma unroll
        for (int j = 0; j < 8; ++j)
            u[j] += ((float)a[j] + (float)b[j]) + ((float)c[j] + (float)d[j]);
    }
    for (; t < end; ++t) {
        int s = csr[t];
        half8 a = *(const half8*)(Mb + (size_t)s * 1024);
        if (FIRST) kacc += (float)Kprev[(size_t)s * 64 + lane];
        #pragma unroll
        for (int j = 0; j < 8; ++j) u[j] += (float)a[j];
    }
    if (Mnext) {
        half8 st;
        #pragma unroll
        for (int j = 0; j < 8; ++j) st[j] = (_Float16)u[j];
        *(half8*)(Mnext + (size_t)node * 1024 + (size_t)chalf * 512 + lane * 8) = st;
    }
    if (FIRST && Knext) Knext[(size_t)node * 64 + lane] = (_Float16)kacc;
    float qd = Q[(size_t)node * 64 + lane];
    #pragma unroll
    for (int j = 0; j < 8; ++j) u[j] *= qd;
    u[0] += __shfl_xor(u[1], 1, 64);
    u[2] += __shfl_xor(u[3], 1, 64);
    u[4] += __shfl_xor(u[5], 1, 64);
    u[6] += __shfl_xor(u[7], 1, 64);
    u[0] += __shfl_xor(u[2], 2, 64);
    u[4] += __shfl_xor(u[6], 2, 64);
    u[0] += __shfl_xor(u[4], 4, 64);
    u[0] += __shfl_xor(u[0], 8, 64);
    float dn;
    if (FIRST) {
        float kq = qd * kacc;
        kq += __shfl_xor(kq, 1, 64);
        kq += __shfl_xor(kq, 2, 64);
        kq += __shfl_xor(kq, 4, 64);
        kq += __shfl_xor(kq, 8, 64);
        dn = kq + CSTE;
        if (p == 0 && den_out) den_out[(size_t)node * NH + h] = dn;
    } else {
        dn = den_in[(size_t)node * NH + h];
    }
    if ((p >> 3) == chalf) {
        float g = gam[h * 4 + hop] / dn;
        hidden[(size_t)node * 64 + lane] += g * u[0];
    }
}

// ================ fallback per-head hop kernels (K in [n][64]) ================
__device__ inline float4 reduce_d(float4 p) {
    #pragma unroll
    for (int m = 4; m <= 32; m <<= 1) {
        p.x += __shfl_xor(p.x, m, 64);
        p.y += __shfl_xor(p.y, m, 64);
        p.z += __shfl_xor(p.z, m, 64);
        p.w += __shfl_xor(p.w, m, 64);
    }
    return p;
}
__device__ inline float reduce_d1(float v) {
    #pragma unroll
    for (int m = 4; m <= 32; m <<= 1) v += __shfl_xor(v, m, 64);
    return v;
}

__global__ __launch_bounds__(256) void hop1h_kernel(
    const float* __restrict__ Q, const _Float16* __restrict__ K0, const float* __restrict__ V,
    const int* __restrict__ offsets, const int* __restrict__ csr,
    const float* __restrict__ gam,
    _Float16* __restrict__ M1, _Float16* __restrict__ K1, float* __restrict__ hidden,
    int N, int h)
{
    int lane = threadIdx.x & 63;
    int node = blockIdx.x * 4 + (threadIdx.x >> 6);
    if (node >= N) return;
    int d = lane >> 2, c0 = (lane & 3) * 4;
    const _Float16* Kb = K0 + h * 16 + d;
    const float* Vb = V + h * CC + c0;
    float4 acc = make_float4(0.f, 0.f, 0.f, 0.f);
    float kacc = 0.f;
    int beg = offsets[node], end = offsets[node + 1];
    for (int t = beg; t < end; ++t) {
        int s = csr[t];
        float kv = (float)Kb[(size_t)s * 64];
        float4 v4 = *(const float4*)(Vb + (size_t)s * HID);
        kacc += kv;
        acc.x += kv * v4.x; acc.y += kv * v4.y;
        acc.z += kv * v4.z; acc.w += kv * v4.w;
    }
    half4 st = { (_Float16)acc.x, (_Float16)acc.y, (_Float16)acc.z, (_Float16)acc.w };
    *(half4*)(M1 + (size_t)node * 256 + lane * 4) = st;
    if ((lane & 3) == 0) K1[(size_t)node * 64 + h * 16 + d] = (_Float16)kacc;
    float qd = Q[(size_t)node * 64 + h * 16 + d];
    float4 pr = make_float4(qd * acc.x, qd * acc.y, qd * acc.z, qd * acc.w);
    pr = reduce_d(pr);
    float den = reduce_d1(qd * kacc) + CSTE;
    if (lane < 4) {
        float g = gam[h * 4 + 1] / den;
        float4* hp = (float4*)(hidden + (size_t)node * 64 + h * CC);
        float4 cur = hp[lane];
        cur.x += g * pr.x; cur.y += g * pr.y; cur.z += g * pr.z; cur.w += g * pr.w;
        hp[lane] = cur;
    }
}

__global__ __launch_bounds__(256) void hop23h_kernel(
    const float* __restrict__ Q, const _Float16* __restrict__ Mprev,
    const _Float16* __restrict__ Kprev,
    const int* __restrict__ offsets, const int* __restrict__ csr,
    const float* __restrict__ gam,
    _Float16* __restrict__ Mnext, _Float16* __restrict__ Knext, float* __restrict__ hidden,
    int N, int h, int hop)
{
    int lane = threadIdx.x & 63;
    int node = blockIdx.x * 4 + (threadIdx.x >> 6);
    if (node >= N) return;
    int d = lane >> 2;
    const _Float16* Kb = Kprev + h * 16 + d;
    float4 acc = make_float4(0.f, 0.f, 0.f, 0.f);
    float kacc = 0.f;
    int beg = offsets[node], end = offsets[node + 1];
    for (int t = beg; t < end; ++t) {
        int s = csr[t];
        half4 m = *(const half4*)(Mprev + (size_t)s * 256 + lane * 4);
        kacc += (float)Kb[(size_t)s * 64];
        acc.x += (float)m.x; acc.y += (float)m.y;
        acc.z += (float)m.z; acc.w += (float)m.w;
    }
    if (Mnext) {
        half4 st = { (_Float16)acc.x, (_Float16)acc.y, (_Float16)acc.z, (_Float16)acc.w };
        *(half4*)(Mnext + (size_t)node * 256 + lane * 4) = st;
        if ((lane & 3) == 0) Knext[(size_t)node * 64 + h * 16 + d] = (_Float16)kacc;
    }
    float qd = Q[(size_t)node * 64 + h * 16 + d];
    float4 pr = make_float4(qd * acc.x, qd * acc.y, qd * acc.z, qd * acc.w);
    pr = reduce_d(pr);
    float den = reduce_d1(qd * kacc) + CSTE;
    if (lane < 4) {
        float g = gam[h * 4 + hop] / den;
        float4* hp = (float4*)(hidden + (size_t)node * 64 + h * CC);
        float4 cur = hp[lane];
        cur.x += g * pr.x; cur.y += g * pr.y; cur.z += g * pr.z; cur.w += g * pr.w;
        hp[lane] = cur;
    }
}

// ---------------- output projection ----------------
__global__ __launch_bounds__(256) void out_kernel(
    const float* __restrict__ hidden, const float* __restrict__ Wo,
    const float* __restrict__ bo, float* __restrict__ out, int N)
{
    __shared__ float wo[HID * CC];
    for (int i = threadIdx.x; i < HID * CC; i += 256) wo[i] = Wo[i];
    __syncthreads();
    int idx = blockIdx.x * 256 + threadIdx.x;
    int n = idx >> 4, c = idx & 15;
    if (n >= N) return;
    float acc = bo[c];
    const float4* hp4 = (const float4*)(hidden + (size_t)n * HID);
    #pragma unroll
    for (int j4 = 0; j4 < 16; ++j4) {
        float4 hv = hp4[j4];
        acc += hv.x * wo[(4 * j4 + 0) * CC + c] + hv.y * wo[(4 * j4 + 1) * CC + c]
             + hv.z * wo[(4 * j4 + 2) * CC + c] + hv.w * wo[(4 * j4 + 3) * CC + c];
    }
    out[(size_t)n * CC + c] = acc;
}

extern "C" void kernel_launch(void* const* d_in, const int* in_sizes, int n_in,
                              void* d_out, int out_size, void* d_ws, size_t ws_size,
                              hipStream_t stream) {
    const float* x       = (const float*)d_in[0];
    const int*   ei      = (const int*)  d_in[1];
    const float* Wi      = (const float*)d_in[2];
    const float* bi      = (const float*)d_in[3];
    const float* Wq      = (const float*)d_in[4];
    const float* bq      = (const float*)d_in[5];
    const float* Wk      = (const float*)d_in[6];
    const float* bk      = (const float*)d_in[7];
    const float* Wv      = (const float*)d_in[8];
    const float* bv      = (const float*)d_in[9];
    const float* Wo      = (const float*)d_in[10];
    const float* bo      = (const float*)d_in[11];
    const float* hopwise = (const float*)d_in[12];
    const float* temp    = (const float*)d_in[13];

    const int N = in_sizes[0] / F_IN;
    const int E = in_sizes[1] / 2;

    char* ws = (char*)d_ws;
    size_t off = 0;
    auto take = [&](size_t bytes) -> char* {
        char* p = ws + off;
        off += (bytes + 255) & ~(size_t)255;
        return p;
    };
    float*    Q      = (float*)take((size_t)N * 64 * 4);
    float*    V      = (float*)take((size_t)N * 64 * 4);
    float*    hidden = (float*)take((size_t)N * 64 * 4);
    _Float16* K0     = (_Float16*)take((size_t)N * 64 * 2);
    _Float16* K1     = (_Float16*)take((size_t)N * 64 * 2);
    _Float16* K2     = (_Float16*)take((size_t)N * 64 * 2);
    float*    den2   = (float*)take((size_t)N * NH * 4);
    float*    den3   = (float*)take((size_t)N * NH * 4);
    float*    gam    = (float*)take(64);
    int*      degcur = (int*)  take((size_t)2 * N * 4);   // deg | cursor
    int*      offs   = (int*)  take((size_t)(N + 1) * 4);
    int*      csr    = (int*)  take((size_t)E * 4);

    // fast path needs 2 × all-head fp16 M buffers (N*1024 halfs each)
    size_t fast_need = off + 2 * (((size_t)N * 1024 * 2 + 255) & ~(size_t)255) + 4096;
    bool fast = (ws_size >= fast_need);

    int* deg    = degcur;
    int* cursor = degcur + N;

    hipMemsetAsync(degcur, 0, (size_t)2 * N * 4, stream);

    gamma_kernel<<<1, 64, 0, stream>>>(hopwise, temp, gam);

    int eb = (E + 255) / 256;
    count_kernel<<<eb, 256, 0, stream>>>(ei, deg, E);
    scan_kernel<<<1, 1024, 0, stream>>>(deg, offs, N);
    scatter_kernel<<<eb, 256, 0, stream>>>(ei, offs, cursor, csr, E);

    int qb = (N + 31) / 32;
    qkv_kernel<<<qb, 256, 0, stream>>>(x, Wi, bi, Wq, bq, Wk, bk, Wv, bv,
                                       gam, Q, K0, V, hidden, N);

    int nb4 = (N + 3) / 4;
    if (fast) {
        _Float16* M1 = (_Float16*)take((size_t)N * 1024 * 2);
        _Float16* M2 = (_Float16*)take((size_t)N * 1024 * 2);
        hop1_all<<<nb4, 256, 0, stream>>>(Q, K0, V, offs, csr, gam, M1, K1, hidden, N);
        // hop 2: two c-half passes (51 MB gathered slice each -> L3-resident)
        hop23_pass<true ><<<nb4, 256, 0, stream>>>(Q, M1, K1, offs, csr, gam,
                                                   M2, K2, den2, (const float*)nullptr,
                                                   hidden, N, 2, 0);
        hop23_pass<false><<<nb4, 256, 0, stream>>>(Q, M1, (const _Float16*)nullptr, offs, csr, gam,
                                                   M2, (_Float16*)nullptr, (float*)nullptr, den2,
                                                   hidden, N, 2, 1);
        // hop 3: two c-half passes, no M store
        hop23_pass<true ><<<nb4, 256, 0, stream>>>(Q, M2, K2, offs, csr, gam,
                                                   (_Float16*)nullptr, (_Float16*)nullptr, den3,
                                                   (const float*)nullptr, hidden, N, 3, 0);
        hop23_pass<false><<<nb4, 256, 0, stream>>>(Q, M2, (const _Float16*)nullptr, offs, csr, gam,
                                                   (_Float16*)nullptr, (_Float16*)nullptr,
                                                   (float*)nullptr, den3, hidden, N, 3, 1);
    } else {
        _Float16* M1 = (_Float16*)take((size_t)N * 256 * 2);
        _Float16* M2 = (_Float16*)take((size_t)N * 256 * 2);
        for (int h = 0; h < NH; ++h) {
            hop1h_kernel<<<nb4, 256, 0, stream>>>(Q, K0, V, offs, csr, gam,
                                                  M1, K1, hidden, N, h);
            hop23h_kernel<<<nb4, 256, 0, stream>>>(Q, M1, K1, offs, csr, gam,
                                                   M2, K2, hidden, N, h, 2);
            hop23h_kernel<<<nb4, 256, 0, stream>>>(Q, M2, K2, offs, csr, gam,
                                                   (_Float16*)nullptr, (_Float16*)nullptr,
                                                   hidden, N, h, 3);
        }
    }

    int ob = (N * CC + 255) / 256;
    out_kernel<<<ob, 256, 0, stream>>>(hidden, Wo, bo, (float*)d_out, N);
}

// Round 6
// 435.097 us; speedup vs baseline: 1.3489x; 1.3489x over previous
//
#include <hip/hip_runtime.h>
#include <math.h>

#define F_IN 128
#define HID  64
#define NH   4
#define DD   16
#define CC   16
#define CSTE 1e-5f

typedef _Float16 half4 __attribute__((ext_vector_type(4)));
typedef _Float16 h2    __attribute__((ext_vector_type(2)));
typedef float    f2    __attribute__((ext_vector_type(2)));

// ---------------- fp8 helpers (OCP e4m3 via hw cvt) ----------------
__device__ __forceinline__ void fp8x16_add(const uint4 m, float* u) {
    const unsigned int w[4] = {m.x, m.y, m.z, m.w};
    #pragma unroll
    for (int q = 0; q < 4; ++q) {
        f2 lo = __builtin_amdgcn_cvt_pk_f32_fp8((int)w[q], false);
        f2 hi = __builtin_amdgcn_cvt_pk_f32_fp8((int)w[q], true);
        u[4 * q + 0] += lo.x; u[4 * q + 1] += lo.y;
        u[4 * q + 2] += hi.x; u[4 * q + 3] += hi.y;
    }
}
__device__ __forceinline__ uint4 fp8x16_pack(const float* u) {
    uint4 r;
    int w;
    w = __builtin_amdgcn_cvt_pk_fp8_f32(u[0],  u[1],  0, false);
    w = __builtin_amdgcn_cvt_pk_fp8_f32(u[2],  u[3],  w, true);
    r.x = (unsigned int)w;
    w = __builtin_amdgcn_cvt_pk_fp8_f32(u[4],  u[5],  0, false);
    w = __builtin_amdgcn_cvt_pk_fp8_f32(u[6],  u[7],  w, true);
    r.y = (unsigned int)w;
    w = __builtin_amdgcn_cvt_pk_fp8_f32(u[8],  u[9],  0, false);
    w = __builtin_amdgcn_cvt_pk_fp8_f32(u[10], u[11], w, true);
    r.z = (unsigned int)w;
    w = __builtin_amdgcn_cvt_pk_fp8_f32(u[12], u[13], 0, false);
    w = __builtin_amdgcn_cvt_pk_fp8_f32(u[14], u[15], w, true);
    r.w = (unsigned int)w;
    return r;
}

// ---------------- gamma precompute (16 floats) ----------------
__global__ void gamma_kernel(const float* __restrict__ hopwise,
                             const float* __restrict__ temp,
                             float* __restrict__ gam) {
    if (threadIdx.x == 0 && blockIdx.x == 0) {
        for (int h = 0; h < NH; ++h) gam[h * 4 + 0] = temp[h * 4 + 0]; // hop0: raw temp
        for (int hop = 1; hop <= 3; ++hop) {
            float m = -1e30f;
            for (int h = 0; h < NH; ++h) m = fmaxf(m, temp[h * 4 + hop]);
            float e[NH], s = 0.f;
            for (int h = 0; h < NH; ++h) { e[h] = expf(temp[h * 4 + hop] - m); s += e[h]; }
            for (int h = 0; h < NH; ++h) gam[h * 4 + hop] = hopwise[hop] * e[h] / s;
        }
    }
}

// ---------------- CSR build ----------------
__global__ void count_kernel(const int* __restrict__ ei, int* __restrict__ deg, int E) {
    int e = blockIdx.x * blockDim.x + threadIdx.x;
    if (e < E) atomicAdd(&deg[ei[E + e]], 1);   // dst = ei[1][e]
}

__global__ void scan_kernel(const int* __restrict__ deg, int* __restrict__ offsets, int N) {
    __shared__ int wsum[16], woff[16];
    __shared__ int carry;
    int lane = threadIdx.x & 63, w = threadIdx.x >> 6;
    if (threadIdx.x == 0) carry = 0;
    __syncthreads();
    for (int base = 0; base < N; base += 4096) {
        int i0 = base + (int)threadIdx.x * 4;
        int d0 = (i0 + 0 < N) ? deg[i0 + 0] : 0;
        int d1 = (i0 + 1 < N) ? deg[i0 + 1] : 0;
        int d2 = (i0 + 2 < N) ? deg[i0 + 2] : 0;
        int d3 = (i0 + 3 < N) ? deg[i0 + 3] : 0;
        int tsum = d0 + d1 + d2 + d3;
        int incl = tsum;
        #pragma unroll
        for (int m = 1; m < 64; m <<= 1) {
            int t = __shfl_up(incl, m, 64);
            if (lane >= m) incl += t;
        }
        if (lane == 63) wsum[w] = incl;
        __syncthreads();
        if (threadIdx.x == 0) {
            int r = carry;
            for (int k = 0; k < 16; ++k) { int t = wsum[k]; woff[k] = r; r += t; }
            carry = r;
        }
        __syncthreads();
        int excl = woff[w] + incl - tsum;
        if (i0 + 0 < N) offsets[i0 + 0] = excl;
        if (i0 + 1 < N) offsets[i0 + 1] = excl + d0;
        if (i0 + 2 < N) offsets[i0 + 2] = excl + d0 + d1;
        if (i0 + 3 < N) offsets[i0 + 3] = excl + d0 + d1 + d2;
        __syncthreads();
    }
    if (threadIdx.x == 0) offsets[N] = carry;
}

__global__ void scatter_kernel(const int* __restrict__ ei, const int* __restrict__ offsets,
                               int* __restrict__ cursor, int* __restrict__ csr, int E) {
    int e = blockIdx.x * blockDim.x + threadIdx.x;
    if (e < E) {
        int src = ei[e];
        int dst = ei[E + e];
        int pos = atomicAdd(&cursor[dst], 1);
        csr[offsets[dst] + pos] = src;
    }
}

// ---------------- QKV + hop-0 hidden (32 nodes/block, 8 nodes/thread) ----------------
__global__ __launch_bounds__(256) void qkv_kernel(
    const float* __restrict__ x,
    const float* __restrict__ Wi, const float* __restrict__ bi,
    const float* __restrict__ Wq, const float* __restrict__ bq,
    const float* __restrict__ Wk, const float* __restrict__ bk,
    const float* __restrict__ Wv, const float* __restrict__ bv,
    const float* __restrict__ gam,
    float* __restrict__ Q, _Float16* __restrict__ K0, float* __restrict__ V,
    unsigned int* __restrict__ V2, float* __restrict__ hidden, int N)
{
    __shared__ float xs[32][F_IN];
    __shared__ float hs[32][HID];
    int t = threadIdx.x;
    int base = blockIdx.x * 32;
    {
        const float4* xg = (const float4*)(x + (size_t)base * F_IN);
        float4* xls = (float4*)&xs[0][0];
        int maxf = min(32, N - base) * (F_IN / 4);
        #pragma unroll
        for (int k = 0; k < 4; ++k) {
            int f = t + k * 256;
            if (f < maxf) xls[f] = xg[f];
        }
    }
    __syncthreads();
    int col = t & 63, w = t >> 6;
    float acc[8];
    #pragma unroll
    for (int i = 0; i < 8; ++i) acc[i] = bi[col];
    for (int j0 = 0; j0 < F_IN; j0 += 4) {
        float w0 = Wi[(j0 + 0) * HID + col];
        float w1 = Wi[(j0 + 1) * HID + col];
        float w2 = Wi[(j0 + 2) * HID + col];
        float w3 = Wi[(j0 + 3) * HID + col];
        #pragma unroll
        for (int i = 0; i < 8; ++i) {
            float4 xv = *(const float4*)&xs[w + 4 * i][j0];
            acc[i] += w0 * xv.x + w1 * xv.y + w2 * xv.z + w3 * xv.w;
        }
    }
    #pragma unroll
    for (int i = 0; i < 8; ++i) hs[w + 4 * i][col] = fmaxf(acc[i], 0.f);
    __syncthreads();
    float aq[8], ak[8], av[8];
    #pragma unroll
    for (int i = 0; i < 8; ++i) { aq[i] = bq[col]; ak[i] = bk[col]; av[i] = bv[col]; }
    for (int j0 = 0; j0 < HID; j0 += 4) {
        float q0 = Wq[(j0 + 0) * HID + col], k0 = Wk[(j0 + 0) * HID + col], v0 = Wv[(j0 + 0) * HID + col];
        float q1 = Wq[(j0 + 1) * HID + col], k1 = Wk[(j0 + 1) * HID + col], v1 = Wv[(j0 + 1) * HID + col];
        float q2 = Wq[(j0 + 2) * HID + col], k2 = Wk[(j0 + 2) * HID + col], v2 = Wv[(j0 + 2) * HID + col];
        float q3 = Wq[(j0 + 3) * HID + col], k3 = Wk[(j0 + 3) * HID + col], v3 = Wv[(j0 + 3) * HID + col];
        #pragma unroll
        for (int i = 0; i < 8; ++i) {
            float4 hv = *(const float4*)&hs[w + 4 * i][j0];
            aq[i] += q0 * hv.x + q1 * hv.y + q2 * hv.z + q3 * hv.w;
            ak[i] += k0 * hv.x + k1 * hv.y + k2 * hv.z + k3 * hv.w;
            av[i] += v0 * hv.x + v1 * hv.y + v2 * hv.z + v3 * hv.w;
        }
    }
    int h = col >> 4;
    float g0 = gam[h * 4 + 0];
    #pragma unroll
    for (int i = 0; i < 8; ++i) {
        int node = base + w + 4 * i;
        float other = __shfl_xor(av[i], 1, 64);
        if (node >= N) continue;
        float qv = (aq[i] > 0.f) ? (1.f + aq[i]) : expf(aq[i]);
        float kv = (ak[i] > 0.f) ? (1.f + ak[i]) : expf(ak[i]);
        Q [(size_t)node * 64 + col] = qv;
        K0[(size_t)node * 64 + col] = (_Float16)kv;
        V [(size_t)node * 64 + col] = av[i];
        if (!(col & 1)) {
            h2 pr; pr.x = (_Float16)av[i]; pr.y = (_Float16)other;
            V2[(size_t)node * 32 + (col >> 1)] = __builtin_bit_cast(unsigned int, pr);
        }
        hidden[(size_t)node * 64 + col] = av[i] * g0;
    }
}

// M layout (fast path): per node 64 uint4 (1024 fp8). Lane (h*16+p), slot j
// holds M[h][d=p][col = p^j].  (round-4 XOR-16 layout, fp8 payload)

// ---------------- shared epilogue (round-4 proven) ----------------
__device__ __forceinline__ void hop_epilogue(
    float* u, float qd, float kacc, const float* gam,
    float* __restrict__ hidden, int node, int lane, int hop)
{
    #pragma unroll
    for (int j = 0; j < 16; ++j) u[j] *= qd;
    #pragma unroll
    for (int m = 1; m < 16; m <<= 1) {
        #pragma unroll
        for (int j = 0; j < 16; ++j) {
            if ((j & (2 * m - 1)) == 0) u[j] += __shfl_xor(u[j | m], m, 64);
        }
    }
    float kq = qd * kacc;
    kq += __shfl_xor(kq, 1, 64);
    kq += __shfl_xor(kq, 2, 64);
    kq += __shfl_xor(kq, 4, 64);
    kq += __shfl_xor(kq, 8, 64);
    float g = gam[(lane >> 4) * 4 + hop] / (kq + CSTE);
    hidden[(size_t)node * 64 + lane] += g * u[0];
}

// ---------------- fast hop 1: all heads, M1 = A (K ⊗ V) fp8, K1 = A K0 ----------------
__global__ __launch_bounds__(256) void hop1_all(
    const float* __restrict__ Q, const _Float16* __restrict__ K0,
    const unsigned int* __restrict__ V2,
    const int* __restrict__ offsets, const int* __restrict__ csr,
    const float* __restrict__ gam,
    uint4* __restrict__ M1, _Float16* __restrict__ K1, float* __restrict__ hidden, int N)
{
    int lane = threadIdx.x & 63;
    int node = blockIdx.x * 4 + (threadIdx.x >> 6);
    if (node >= N) return;
    int p = lane & 15;
    int pb = (lane & 48) >> 1;   // 8*h — pair-index base of this head
    int ph = p >> 1;
    float u[16];
    #pragma unroll
    for (int j = 0; j < 16; ++j) u[j] = 0.f;
    float kacc = 0.f;
    int beg = offsets[node], end = offsets[node + 1];
    int t = beg;
    for (; t + 1 < end; t += 2) {
        int s0 = csr[t], s1 = csr[t + 1];
        unsigned int vp0 = V2[(size_t)s0 * 32 + (lane & 31)];
        unsigned int vp1 = V2[(size_t)s1 * 32 + (lane & 31)];
        float k0 = (float)K0[(size_t)s0 * 64 + lane];
        float k1 = (float)K0[(size_t)s1 * 64 + lane];
        kacc += k0 + k1;
        #pragma unroll
        for (int t8 = 0; t8 < 8; ++t8) {
            int src = pb + (ph ^ t8);
            unsigned int w0 = (unsigned int)__shfl((int)vp0, src, 64);
            unsigned int w1 = (unsigned int)__shfl((int)vp1, src, 64);
            h2 a = __builtin_bit_cast(h2, w0);
            h2 b = __builtin_bit_cast(h2, w1);
            u[2 * t8 + 0] += k0 * (float)a.x + k1 * (float)b.x;
            u[2 * t8 + 1] += k0 * (float)a.y + k1 * (float)b.y;
        }
    }
    for (; t < end; ++t) {
        int s = csr[t];
        unsigned int vp = V2[(size_t)s * 32 + (lane & 31)];
        float kk = (float)K0[(size_t)s * 64 + lane];
        kacc += kk;
        #pragma unroll
        for (int t8 = 0; t8 < 8; ++t8) {
            unsigned int w0 = (unsigned int)__shfl((int)vp, pb + (ph ^ t8), 64);
            h2 a = __builtin_bit_cast(h2, w0);
            u[2 * t8 + 0] += kk * (float)a.x;
            u[2 * t8 + 1] += kk * (float)a.y;
        }
    }
    // odd d-lanes accumulated (hi,lo) order — swap once to restore col = p^j
    if (p & 1) {
        #pragma unroll
        for (int t8 = 0; t8 < 8; ++t8) {
            float tmp = u[2 * t8]; u[2 * t8] = u[2 * t8 + 1]; u[2 * t8 + 1] = tmp;
        }
    }
    M1[(size_t)node * 64 + lane] = fp8x16_pack(u);
    K1[(size_t)node * 64 + lane] = (_Float16)kacc;
    float qd = Q[(size_t)node * 64 + lane];
    hop_epilogue(u, qd, kacc, gam, hidden, node, lane, 1);
}

// ---------------- fast hops 2/3: single pass, fp8 M gather ----------------
template<bool STORE>
__global__ __launch_bounds__(256) void hop23_all(
    const float* __restrict__ Q, const uint4* __restrict__ Mprev,
    const _Float16* __restrict__ Kprev,
    const int* __restrict__ offsets, const int* __restrict__ csr,
    const float* __restrict__ gam,
    uint4* __restrict__ Mnext, _Float16* __restrict__ Knext,
    float* __restrict__ hidden, int N, int hop)
{
    int lane = threadIdx.x & 63;
    int node = blockIdx.x * 4 + (threadIdx.x >> 6);
    if (node >= N) return;
    const uint4* Mb = Mprev + lane;
    float u[16];
    #pragma unroll
    for (int j = 0; j < 16; ++j) u[j] = 0.f;
    float kacc = 0.f;
    int beg = offsets[node], end = offsets[node + 1];
    int t = beg;
    for (; t + 3 < end; t += 4) {
        int s0 = csr[t], s1 = csr[t + 1], s2 = csr[t + 2], s3 = csr[t + 3];
        uint4 m0 = Mb[(size_t)s0 * 64];
        uint4 m1 = Mb[(size_t)s1 * 64];
        uint4 m2 = Mb[(size_t)s2 * 64];
        uint4 m3 = Mb[(size_t)s3 * 64];
        kacc += ((float)Kprev[(size_t)s0 * 64 + lane] + (float)Kprev[(size_t)s1 * 64 + lane])
              + ((float)Kprev[(size_t)s2 * 64 + lane] + (float)Kprev[(size_t)s3 * 64 + lane]);
        fp8x16_add(m0, u);
        fp8x16_add(m1, u);
        fp8x16_add(m2, u);
        fp8x16_add(m3, u);
    }
    for (; t < end; ++t) {
        int s = csr[t];
        uint4 m = Mb[(size_t)s * 64];
        kacc += (float)Kprev[(size_t)s * 64 + lane];
        fp8x16_add(m, u);
    }
    if (STORE) {
        Mnext[(size_t)node * 64 + lane] = fp8x16_pack(u);
        Knext[(size_t)node * 64 + lane] = (_Float16)kacc;
    }
    float qd = Q[(size_t)node * 64 + lane];
    hop_epilogue(u, qd, kacc, gam, hidden, node, lane, hop);
}

// ================ fallback per-head hop kernels (K in [n][64]) ================
__device__ inline float4 reduce_d(float4 p) {
    #pragma unroll
    for (int m = 4; m <= 32; m <<= 1) {
        p.x += __shfl_xor(p.x, m, 64);
        p.y += __shfl_xor(p.y, m, 64);
        p.z += __shfl_xor(p.z, m, 64);
        p.w += __shfl_xor(p.w, m, 64);
    }
    return p;
}
__device__ inline float reduce_d1(float v) {
    #pragma unroll
    for (int m = 4; m <= 32; m <<= 1) v += __shfl_xor(v, m, 64);
    return v;
}

__global__ __launch_bounds__(256) void hop1h_kernel(
    const float* __restrict__ Q, const _Float16* __restrict__ K0, const float* __restrict__ V,
    const int* __restrict__ offsets, const int* __restrict__ csr,
    const float* __restrict__ gam,
    _Float16* __restrict__ M1, _Float16* __restrict__ K1, float* __restrict__ hidden,
    int N, int h)
{
    int lane = threadIdx.x & 63;
    int node = blockIdx.x * 4 + (threadIdx.x >> 6);
    if (node >= N) return;
    int d = lane >> 2, c0 = (lane & 3) * 4;
    const _Float16* Kb = K0 + h * 16 + d;
    const float* Vb = V + h * CC + c0;
    float4 acc = make_float4(0.f, 0.f, 0.f, 0.f);
    float kacc = 0.f;
    int beg = offsets[node], end = offsets[node + 1];
    for (int t = beg; t < end; ++t) {
        int s = csr[t];
        float kv = (float)Kb[(size_t)s * 64];
        float4 v4 = *(const float4*)(Vb + (size_t)s * HID);
        kacc += kv;
        acc.x += kv * v4.x; acc.y += kv * v4.y;
        acc.z += kv * v4.z; acc.w += kv * v4.w;
    }
    half4 st = { (_Float16)acc.x, (_Float16)acc.y, (_Float16)acc.z, (_Float16)acc.w };
    *(half4*)(M1 + (size_t)node * 256 + lane * 4) = st;
    if ((lane & 3) == 0) K1[(size_t)node * 64 + h * 16 + d] = (_Float16)kacc;
    float qd = Q[(size_t)node * 64 + h * 16 + d];
    float4 pr = make_float4(qd * acc.x, qd * acc.y, qd * acc.z, qd * acc.w);
    pr = reduce_d(pr);
    float den = reduce_d1(qd * kacc) + CSTE;
    if (lane < 4) {
        float g = gam[h * 4 + 1] / den;
        float4* hp = (float4*)(hidden + (size_t)node * 64 + h * CC);
        float4 cur = hp[lane];
        cur.x += g * pr.x; cur.y += g * pr.y; cur.z += g * pr.z; cur.w += g * pr.w;
        hp[lane] = cur;
    }
}

__global__ __launch_bounds__(256) void hop23h_kernel(
    const float* __restrict__ Q, const _Float16* __restrict__ Mprev,
    const _Float16* __restrict__ Kprev,
    const int* __restrict__ offsets, const int* __restrict__ csr,
    const float* __restrict__ gam,
    _Float16* __restrict__ Mnext, _Float16* __restrict__ Knext, float* __restrict__ hidden,
    int N, int h, int hop)
{
    int lane = threadIdx.x & 63;
    int node = blockIdx.x * 4 + (threadIdx.x >> 6);
    if (node >= N) return;
    int d = lane >> 2;
    const _Float16* Kb = Kprev + h * 16 + d;
    float4 acc = make_float4(0.f, 0.f, 0.f, 0.f);
    float kacc = 0.f;
    int beg = offsets[node], end = offsets[node + 1];
    for (int t = beg; t < end; ++t) {
        int s = csr[t];
        half4 m = *(const half4*)(Mprev + (size_t)s * 256 + lane * 4);
        kacc += (float)Kb[(size_t)s * 64];
        acc.x += (float)m.x; acc.y += (float)m.y;
        acc.z += (float)m.z; acc.w += (float)m.w;
    }
    if (Mnext) {
        half4 st = { (_Float16)acc.x, (_Float16)acc.y, (_Float16)acc.z, (_Float16)acc.w };
        *(half4*)(Mnext + (size_t)node * 256 + lane * 4) = st;
        if ((lane & 3) == 0) Knext[(size_t)node * 64 + h * 16 + d] = (_Float16)kacc;
    }
    float qd = Q[(size_t)node * 64 + h * 16 + d];
    float4 pr = make_float4(qd * acc.x, qd * acc.y, qd * acc.z, qd * acc.w);
    pr = reduce_d(pr);
    float den = reduce_d1(qd * kacc) + CSTE;
    if (lane < 4) {
        float g = gam[h * 4 + hop] / den;
        float4* hp = (float4*)(hidden + (size_t)node * 64 + h * CC);
        float4 cur = hp[lane];
        cur.x += g * pr.x; cur.y += g * pr.y; cur.z += g * pr.z; cur.w += g * pr.w;
        hp[lane] = cur;
    }
}

// ---------------- output projection ----------------
__global__ __launch_bounds__(256) void out_kernel(
    const float* __restrict__ hidden, const float* __restrict__ Wo,
    const float* __restrict__ bo, float* __restrict__ out, int N)
{
    __shared__ float wo[HID * CC];
    for (int i = threadIdx.x; i < HID * CC; i += 256) wo[i] = Wo[i];
    __syncthreads();
    int idx = blockIdx.x * 256 + threadIdx.x;
    int n = idx >> 4, c = idx & 15;
    if (n >= N) return;
    float acc = bo[c];
    const float4* hp4 = (const float4*)(hidden + (size_t)n * HID);
    #pragma unroll
    for (int j4 = 0; j4 < 16; ++j4) {
        float4 hv = hp4[j4];
        acc += hv.x * wo[(4 * j4 + 0) * CC + c] + hv.y * wo[(4 * j4 + 1) * CC + c]
             + hv.z * wo[(4 * j4 + 2) * CC + c] + hv.w * wo[(4 * j4 + 3) * CC + c];
    }
    out[(size_t)n * CC + c] = acc;
}

extern "C" void kernel_launch(void* const* d_in, const int* in_sizes, int n_in,
                              void* d_out, int out_size, void* d_ws, size_t ws_size,
                              hipStream_t stream) {
    const float* x       = (const float*)d_in[0];
    const int*   ei      = (const int*)  d_in[1];
    const float* Wi      = (const float*)d_in[2];
    const float* bi      = (const float*)d_in[3];
    const float* Wq      = (const float*)d_in[4];
    const float* bq      = (const float*)d_in[5];
    const float* Wk      = (const float*)d_in[6];
    const float* bk      = (const float*)d_in[7];
    const float* Wv      = (const float*)d_in[8];
    const float* bv      = (const float*)d_in[9];
    const float* Wo      = (const float*)d_in[10];
    const float* bo      = (const float*)d_in[11];
    const float* hopwise = (const float*)d_in[12];
    const float* temp    = (const float*)d_in[13];

    const int N = in_sizes[0] / F_IN;
    const int E = in_sizes[1] / 2;

    char* ws = (char*)d_ws;
    size_t off = 0;
    auto take = [&](size_t bytes) -> char* {
        char* p = ws + off;
        off += (bytes + 255) & ~(size_t)255;
        return p;
    };
    float*        Q      = (float*)take((size_t)N * 64 * 4);
    float*        V      = (float*)take((size_t)N * 64 * 4);
    unsigned int* V2     = (unsigned int*)take((size_t)N * 32 * 4);
    float*        hidden = (float*)take((size_t)N * 64 * 4);
    _Float16*     K0     = (_Float16*)take((size_t)N * 64 * 2);
    _Float16*     K1     = (_Float16*)take((size_t)N * 64 * 2);
    _Float16*     K2     = (_Float16*)take((size_t)N * 64 * 2);
    float*        gam    = (float*)take(64);
    int*          degcur = (int*)  take((size_t)2 * N * 4);   // deg | cursor
    int*          offs   = (int*)  take((size_t)(N + 1) * 4);
    int*          csr    = (int*)  take((size_t)E * 4);

    // fast path needs 2 × all-head fp8 M buffers (N*1024 bytes each)
    size_t fast_need = off + 2 * (((size_t)N * 1024 + 255) & ~(size_t)255) + 4096;
    bool fast = (ws_size >= fast_need);

    int* deg    = degcur;
    int* cursor = degcur + N;

    hipMemsetAsync(degcur, 0, (size_t)2 * N * 4, stream);

    gamma_kernel<<<1, 64, 0, stream>>>(hopwise, temp, gam);

    int eb = (E + 255) / 256;
    count_kernel<<<eb, 256, 0, stream>>>(ei, deg, E);
    scan_kernel<<<1, 1024, 0, stream>>>(deg, offs, N);
    scatter_kernel<<<eb, 256, 0, stream>>>(ei, offs, cursor, csr, E);

    int qb = (N + 31) / 32;
    qkv_kernel<<<qb, 256, 0, stream>>>(x, Wi, bi, Wq, bq, Wk, bk, Wv, bv,
                                       gam, Q, K0, V, V2, hidden, N);

    int nb4 = (N + 3) / 4;
    if (fast) {
        uint4* M1 = (uint4*)take((size_t)N * 1024);
        uint4* M2 = (uint4*)take((size_t)N * 1024);
        hop1_all<<<nb4, 256, 0, stream>>>(Q, K0, V2, offs, csr, gam, M1, K1, hidden, N);
        hop23_all<true ><<<nb4, 256, 0, stream>>>(Q, M1, K1, offs, csr, gam,
                                                  M2, K2, hidden, N, 2);
        hop23_all<false><<<nb4, 256, 0, stream>>>(Q, M2, K2, offs, csr, gam,
                                                  (uint4*)nullptr, (_Float16*)nullptr,
                                                  hidden, N, 3);
    } else {
        _Float16* M1 = (_Float16*)take((size_t)N * 256 * 2);
        _Float16* M2 = (_Float16*)take((size_t)N * 256 * 2);
        for (int h = 0; h < NH; ++h) {
            hop1h_kernel<<<nb4, 256, 0, stream>>>(Q, K0, V, offs, csr, gam,
                                                  M1, K1, hidden, N, h);
            hop23h_kernel<<<nb4, 256, 0, stream>>>(Q, M1, K1, offs, csr, gam,
                                                   M2, K2, hidden, N, h, 2);
            hop23h_kernel<<<nb4, 256, 0, stream>>>(Q, M2, K2, offs, csr, gam,
                                                   (_Float16*)nullptr, (_Float16*)nullptr,
                                                   hidden, N, h, 3);
        }
    }

    int ob = (N * CC + 255) / 256;
    out_kernel<<<ob, 256, 0, stream>>>(hidden, Wo, bo, (float*)d_out, N);
}

// Round 7
// 389.695 us; speedup vs baseline: 1.5061x; 1.1165x over previous
//
#include <hip/hip_runtime.h>
#include <math.h>

#define F_IN 128
#define HID  64
#define NH   4
#define DD   16
#define CC   16
#define CSTE 1e-5f

typedef _Float16 half4 __attribute__((ext_vector_type(4)));
typedef _Float16 h2    __attribute__((ext_vector_type(2)));
typedef float    f2    __attribute__((ext_vector_type(2)));
typedef short    short8 __attribute__((ext_vector_type(8)));
typedef float    f4v   __attribute__((ext_vector_type(4)));

// LDS strides (elements) — padded so b128 frag reads are ≤2-way bank conflicts
#define WIT_LD 136   // 128 + 8, 272 B rows (16B aligned)
#define W2T_LD 72    // 64 + 8, 144 B rows
#define H_LD   72

__device__ __forceinline__ unsigned short bf16r(float f) {
    unsigned int u = __builtin_bit_cast(unsigned int, f);
    unsigned int r = (u + 0x7FFFu + ((u >> 16) & 1u)) >> 16;
    return (unsigned short)r;
}

// ---------------- fp8 helpers (OCP e4m3 via hw cvt) ----------------
__device__ __forceinline__ void fp8x16_add(const uint4 m, float* u) {
    const unsigned int w[4] = {m.x, m.y, m.z, m.w};
    #pragma unroll
    for (int q = 0; q < 4; ++q) {
        f2 lo = __builtin_amdgcn_cvt_pk_f32_fp8((int)w[q], false);
        f2 hi = __builtin_amdgcn_cvt_pk_f32_fp8((int)w[q], true);
        u[4 * q + 0] += lo.x; u[4 * q + 1] += lo.y;
        u[4 * q + 2] += hi.x; u[4 * q + 3] += hi.y;
    }
}
__device__ __forceinline__ uint4 fp8x16_pack(const float* u) {
    uint4 r;
    int w;
    w = __builtin_amdgcn_cvt_pk_fp8_f32(u[0],  u[1],  0, false);
    w = __builtin_amdgcn_cvt_pk_fp8_f32(u[2],  u[3],  w, true);
    r.x = (unsigned int)w;
    w = __builtin_amdgcn_cvt_pk_fp8_f32(u[4],  u[5],  0, false);
    w = __builtin_amdgcn_cvt_pk_fp8_f32(u[6],  u[7],  w, true);
    r.y = (unsigned int)w;
    w = __builtin_amdgcn_cvt_pk_fp8_f32(u[8],  u[9],  0, false);
    w = __builtin_amdgcn_cvt_pk_fp8_f32(u[10], u[11], w, true);
    r.z = (unsigned int)w;
    w = __builtin_amdgcn_cvt_pk_fp8_f32(u[12], u[13], 0, false);
    w = __builtin_amdgcn_cvt_pk_fp8_f32(u[14], u[15], w, true);
    r.w = (unsigned int)w;
    return r;
}

// ---------------- gamma precompute (16 floats) ----------------
__global__ void gamma_kernel(const float* __restrict__ hopwise,
                             const float* __restrict__ temp,
                             float* __restrict__ gam) {
    if (threadIdx.x == 0 && blockIdx.x == 0) {
        for (int h = 0; h < NH; ++h) gam[h * 4 + 0] = temp[h * 4 + 0]; // hop0: raw temp
        for (int hop = 1; hop <= 3; ++hop) {
            float m = -1e30f;
            for (int h = 0; h < NH; ++h) m = fmaxf(m, temp[h * 4 + hop]);
            float e[NH], s = 0.f;
            for (int h = 0; h < NH; ++h) { e[h] = expf(temp[h * 4 + hop] - m); s += e[h]; }
            for (int h = 0; h < NH; ++h) gam[h * 4 + hop] = hopwise[hop] * e[h] / s;
        }
    }
}

// ---------------- CSR build ----------------
__global__ void count_kernel(const int* __restrict__ ei, int* __restrict__ deg, int E) {
    int e = blockIdx.x * blockDim.x + threadIdx.x;
    if (e < E) atomicAdd(&deg[ei[E + e]], 1);   // dst = ei[1][e]
}

// 3-kernel scan: per-4096-block local scan -> scan of block sums -> add base
__global__ __launch_bounds__(1024) void scan_a(const int* __restrict__ deg,
                                               int* __restrict__ offsets,
                                               int* __restrict__ bsum, int N) {
    __shared__ int wsum[16], woff[16];
    int lane = threadIdx.x & 63, w = threadIdx.x >> 6;
    int i0 = blockIdx.x * 4096 + (int)threadIdx.x * 4;
    int d0 = (i0 + 0 < N) ? deg[i0 + 0] : 0;
    int d1 = (i0 + 1 < N) ? deg[i0 + 1] : 0;
    int d2 = (i0 + 2 < N) ? deg[i0 + 2] : 0;
    int d3 = (i0 + 3 < N) ? deg[i0 + 3] : 0;
    int tsum = d0 + d1 + d2 + d3;
    int incl = tsum;
    #pragma unroll
    for (int m = 1; m < 64; m <<= 1) {
        int t = __shfl_up(incl, m, 64);
        if (lane >= m) incl += t;
    }
    if (lane == 63) wsum[w] = incl;
    __syncthreads();
    if (threadIdx.x == 0) {
        int r = 0;
        for (int k = 0; k < 16; ++k) { int t = wsum[k]; woff[k] = r; r += t; }
        bsum[blockIdx.x] = r;
    }
    __syncthreads();
    int excl = woff[w] + incl - tsum;   // block-local exclusive
    if (i0 + 0 < N) offsets[i0 + 0] = excl;
    if (i0 + 1 < N) offsets[i0 + 1] = excl + d0;
    if (i0 + 2 < N) offsets[i0 + 2] = excl + d0 + d1;
    if (i0 + 3 < N) offsets[i0 + 3] = excl + d0 + d1 + d2;
}

__global__ void scan_b(int* __restrict__ bsum, int* __restrict__ bbase,
                       int* __restrict__ offsets, int nb, int N) {
    if (threadIdx.x == 0) {
        int r = 0;
        for (int i = 0; i < nb; ++i) { int t = bsum[i]; bbase[i] = r; r += t; }
        offsets[N] = r;
    }
}

__global__ void scan_c(int* __restrict__ offsets, const int* __restrict__ bbase, int N) {
    int i = blockIdx.x * blockDim.x + threadIdx.x;
    if (i < N) offsets[i] += bbase[i >> 12];
}

__global__ void scatter_kernel(const int* __restrict__ ei, const int* __restrict__ offsets,
                               int* __restrict__ cursor, int* __restrict__ csr, int E) {
    int e = blockIdx.x * blockDim.x + threadIdx.x;
    if (e < E) {
        int src = ei[e];
        int dst = ei[E + e];
        int pos = atomicAdd(&cursor[dst], 1);
        csr[offsets[dst] + pos] = src;
    }
}

// ---------------- MFMA QKV: 64 nodes/block, 4 waves ----------------
// stage1: h = relu(x@Wi+bi)  (M=64,K=128,N=64), stage2: [Q|K|V] = h@W2+b (N=192)
__global__ __launch_bounds__(256) void qkv_mfma(
    const float* __restrict__ x,
    const float* __restrict__ Wi, const float* __restrict__ bi,
    const float* __restrict__ Wq, const float* __restrict__ bq,
    const float* __restrict__ Wk, const float* __restrict__ bk,
    const float* __restrict__ Wv, const float* __restrict__ bv,
    const float* __restrict__ gam,
    float* __restrict__ Q, _Float16* __restrict__ K0, float* __restrict__ V,
    unsigned int* __restrict__ V2, float* __restrict__ hidden, int N)
{
    __shared__ unsigned short wit[64 * WIT_LD];    // Wi^T  [n][k]
    __shared__ unsigned short w2t[192 * W2T_LD];   // W2^T  [n][k] (Wq|Wk|Wv cols)
    __shared__ unsigned short hlds[64 * H_LD];     // h     [node][k]
    int t = threadIdx.x;
    // stage weights (bf16, transposed)
    #pragma unroll
    for (int i = 0; i < 32; ++i) {
        int g = t + i * 256;                       // 8192 = 128*64
        wit[(g & 63) * WIT_LD + (g >> 6)] = bf16r(Wi[g]);
    }
    #pragma unroll
    for (int i = 0; i < 16; ++i) {
        int g = t + i * 256;                       // 4096 = 64*64
        int k = g >> 6, n = g & 63;
        w2t[(n      ) * W2T_LD + k] = bf16r(Wq[g]);
        w2t[(n +  64) * W2T_LD + k] = bf16r(Wk[g]);
        w2t[(n + 128) * W2T_LD + k] = bf16r(Wv[g]);
    }
    __syncthreads();

    int lane = t & 63, w = t >> 6;
    int p = lane & 15, quad = lane >> 4;
    int mbase = blockIdx.x * 64 + w * 16;

    // ---- stage 1 ----
    short8 afrag[4];
    {
        int node = mbase + p;
        if (node >= N) node = N - 1;               // clamped read; store guarded
        const float* xr = x + (size_t)node * F_IN + quad * 8;
        #pragma unroll
        for (int ks = 0; ks < 4; ++ks) {
            float4 a0 = *(const float4*)(xr + ks * 32);
            float4 a1 = *(const float4*)(xr + ks * 32 + 4);
            short8 f;
            f[0] = bf16r(a0.x); f[1] = bf16r(a0.y); f[2] = bf16r(a0.z); f[3] = bf16r(a0.w);
            f[4] = bf16r(a1.x); f[5] = bf16r(a1.y); f[6] = bf16r(a1.z); f[7] = bf16r(a1.w);
            afrag[ks] = f;
        }
    }
    #pragma unroll
    for (int nt = 0; nt < 4; ++nt) {
        f4v acc = {0.f, 0.f, 0.f, 0.f};
        #pragma unroll
        for (int ks = 0; ks < 4; ++ks) {
            short8 b = *(const short8*)&wit[(nt * 16 + p) * WIT_LD + ks * 32 + quad * 8];
            acc = __builtin_amdgcn_mfma_f32_16x16x32_bf16(afrag[ks], b, acc, 0, 0, 0);
        }
        float bb = bi[nt * 16 + p];
        #pragma unroll
        for (int r = 0; r < 4; ++r) {
            float hv = fmaxf(acc[r] + bb, 0.f);
            hlds[(w * 16 + quad * 4 + r) * H_LD + nt * 16 + p] = bf16r(hv);
        }
    }
    __syncthreads();

    // ---- stage 2 ----
    short8 ha0 = *(const short8*)&hlds[(w * 16 + p) * H_LD + quad * 8];
    short8 ha1 = *(const short8*)&hlds[(w * 16 + p) * H_LD + 32 + quad * 8];
    int node_r = mbase + quad * 4;
    #pragma unroll
    for (int nt = 0; nt < 12; ++nt) {
        f4v acc = {0.f, 0.f, 0.f, 0.f};
        short8 b0 = *(const short8*)&w2t[(nt * 16 + p) * W2T_LD + quad * 8];
        short8 b1 = *(const short8*)&w2t[(nt * 16 + p) * W2T_LD + 32 + quad * 8];
        acc = __builtin_amdgcn_mfma_f32_16x16x32_bf16(ha0, b0, acc, 0, 0, 0);
        acc = __builtin_amdgcn_mfma_f32_16x16x32_bf16(ha1, b1, acc, 0, 0, 0);
        int col = nt * 16 + p;                    // 0..191, branch wave-uniform per nt
        #pragma unroll
        for (int r = 0; r < 4; ++r) {
            int node = node_r + r;
            float v = acc[r];
            if (col < 64) {
                if (node >= N) continue;
                v += bq[col];
                Q[(size_t)node * 64 + col] = (v > 0.f) ? (1.f + v) : __expf(v);
            } else if (col < 128) {
                if (node >= N) continue;
                int c = col - 64;
                v += bk[c];
                K0[(size_t)node * 64 + c] = (_Float16)((v > 0.f) ? (1.f + v) : __expf(v));
            } else {
                int c = col - 128;
                v += bv[c];
                float other = __shfl_xor(v, 1, 64);   // partner has same node
                if (node >= N) continue;
                V[(size_t)node * 64 + c] = v;
                hidden[(size_t)node * 64 + c] = v * gam[(c >> 4) * 4];
                if (!(c & 1)) {
                    h2 pr; pr.x = (_Float16)v; pr.y = (_Float16)other;
                    V2[(size_t)node * 32 + (c >> 1)] = __builtin_bit_cast(unsigned int, pr);
                }
            }
        }
    }
}

// M layout (fast path): per node 64 uint4 (1024 fp8). Lane (h*16+p), slot j
// holds M[h][d=p][col = p^j].

// ---------------- shared epilogue ----------------
__device__ __forceinline__ void hop_epilogue(
    float* u, float qd, float kacc, const float* gam,
    float* __restrict__ hidden, int node, int lane, int hop)
{
    #pragma unroll
    for (int j = 0; j < 16; ++j) u[j] *= qd;
    #pragma unroll
    for (int m = 1; m < 16; m <<= 1) {
        #pragma unroll
        for (int j = 0; j < 16; ++j) {
            if ((j & (2 * m - 1)) == 0) u[j] += __shfl_xor(u[j | m], m, 64);
        }
    }
    float kq = qd * kacc;
    kq += __shfl_xor(kq, 1, 64);
    kq += __shfl_xor(kq, 2, 64);
    kq += __shfl_xor(kq, 4, 64);
    kq += __shfl_xor(kq, 8, 64);
    float g = gam[(lane >> 4) * 4 + hop] / (kq + CSTE);
    hidden[(size_t)node * 64 + lane] += g * u[0];
}

// ---------------- fast hop 1: all heads, M1 = A (K ⊗ V) fp8, K1 = A K0 ----------------
__global__ __launch_bounds__(256) void hop1_all(
    const float* __restrict__ Q, const _Float16* __restrict__ K0,
    const unsigned int* __restrict__ V2,
    const int* __restrict__ offsets, const int* __restrict__ csr,
    const float* __restrict__ gam,
    uint4* __restrict__ M1, _Float16* __restrict__ K1, float* __restrict__ hidden, int N)
{
    int lane = threadIdx.x & 63;
    int node = blockIdx.x * 4 + (threadIdx.x >> 6);
    if (node >= N) return;
    int p = lane & 15;
    int pb = (lane & 48) >> 1;   // 8*h — pair-index base of this head
    int ph = p >> 1;
    float u[16];
    #pragma unroll
    for (int j = 0; j < 16; ++j) u[j] = 0.f;
    float kacc = 0.f;
    int beg = offsets[node], end = offsets[node + 1];
    int t = beg;
    for (; t + 3 < end; t += 4) {
        int s0 = csr[t], s1 = csr[t + 1], s2 = csr[t + 2], s3 = csr[t + 3];
        unsigned int vp0 = V2[(size_t)s0 * 32 + (lane & 31)];
        unsigned int vp1 = V2[(size_t)s1 * 32 + (lane & 31)];
        unsigned int vp2 = V2[(size_t)s2 * 32 + (lane & 31)];
        unsigned int vp3 = V2[(size_t)s3 * 32 + (lane & 31)];
        float k0 = (float)K0[(size_t)s0 * 64 + lane];
        float k1 = (float)K0[(size_t)s1 * 64 + lane];
        float k2 = (float)K0[(size_t)s2 * 64 + lane];
        float k3 = (float)K0[(size_t)s3 * 64 + lane];
        kacc += (k0 + k1) + (k2 + k3);
        #pragma unroll
        for (int t8 = 0; t8 < 8; ++t8) {
            int src = pb + (ph ^ t8);
            h2 a = __builtin_bit_cast(h2, (unsigned int)__shfl((int)vp0, src, 64));
            h2 b = __builtin_bit_cast(h2, (unsigned int)__shfl((int)vp1, src, 64));
            h2 c = __builtin_bit_cast(h2, (unsigned int)__shfl((int)vp2, src, 64));
            h2 d = __builtin_bit_cast(h2, (unsigned int)__shfl((int)vp3, src, 64));
            u[2 * t8 + 0] += (k0 * (float)a.x + k1 * (float)b.x) + (k2 * (float)c.x + k3 * (float)d.x);
            u[2 * t8 + 1] += (k0 * (float)a.y + k1 * (float)b.y) + (k2 * (float)c.y + k3 * (float)d.y);
        }
    }
    for (; t < end; ++t) {
        int s = csr[t];
        unsigned int vp = V2[(size_t)s * 32 + (lane & 31)];
        float kk = (float)K0[(size_t)s * 64 + lane];
        kacc += kk;
        #pragma unroll
        for (int t8 = 0; t8 < 8; ++t8) {
            h2 a = __builtin_bit_cast(h2, (unsigned int)__shfl((int)vp, pb + (ph ^ t8), 64));
            u[2 * t8 + 0] += kk * (float)a.x;
            u[2 * t8 + 1] += kk * (float)a.y;
        }
    }
    // odd d-lanes accumulated (hi,lo) order — swap once to restore col = p^j
    if (p & 1) {
        #pragma unroll
        for (int t8 = 0; t8 < 8; ++t8) {
            float tmp = u[2 * t8]; u[2 * t8] = u[2 * t8 + 1]; u[2 * t8 + 1] = tmp;
        }
    }
    M1[(size_t)node * 64 + lane] = fp8x16_pack(u);
    K1[(size_t)node * 64 + lane] = (_Float16)kacc;
    float qd = Q[(size_t)node * 64 + lane];
    hop_epilogue(u, qd, kacc, gam, hidden, node, lane, 1);
}

// ---------------- fast hops 2/3: single pass, fp8 M gather ----------------
template<bool STORE>
__global__ __launch_bounds__(256) void hop23_all(
    const float* __restrict__ Q, const uint4* __restrict__ Mprev,
    const _Float16* __restrict__ Kprev,
    const int* __restrict__ offsets, const int* __restrict__ csr,
    const float* __restrict__ gam,
    uint4* __restrict__ Mnext, _Float16* __restrict__ Knext,
    float* __restrict__ hidden, int N, int hop)
{
    int lane = threadIdx.x & 63;
    int node = blockIdx.x * 4 + (threadIdx.x >> 6);
    if (node >= N) return;
    const uint4* Mb = Mprev + lane;
    float u[16];
    #pragma unroll
    for (int j = 0; j < 16; ++j) u[j] = 0.f;
    float kacc = 0.f;
    int beg = offsets[node], end = offsets[node + 1];
    int t = beg;
    for (; t + 3 < end; t += 4) {
        int s0 = csr[t], s1 = csr[t + 1], s2 = csr[t + 2], s3 = csr[t + 3];
        uint4 m0 = Mb[(size_t)s0 * 64];
        uint4 m1 = Mb[(size_t)s1 * 64];
        uint4 m2 = Mb[(size_t)s2 * 64];
        uint4 m3 = Mb[(size_t)s3 * 64];
        kacc += ((float)Kprev[(size_t)s0 * 64 + lane] + (float)Kprev[(size_t)s1 * 64 + lane])
              + ((float)Kprev[(size_t)s2 * 64 + lane] + (float)Kprev[(size_t)s3 * 64 + lane]);
        fp8x16_add(m0, u);
        fp8x16_add(m1, u);
        fp8x16_add(m2, u);
        fp8x16_add(m3, u);
    }
    for (; t < end; ++t) {
        int s = csr[t];
        uint4 m = Mb[(size_t)s * 64];
        kacc += (float)Kprev[(size_t)s * 64 + lane];
        fp8x16_add(m, u);
    }
    if (STORE) {
        Mnext[(size_t)node * 64 + lane] = fp8x16_pack(u);
        Knext[(size_t)node * 64 + lane] = (_Float16)kacc;
    }
    float qd = Q[(size_t)node * 64 + lane];
    hop_epilogue(u, qd, kacc, gam, hidden, node, lane, hop);
}

// ================ fallback per-head hop kernels ================
__device__ inline float4 reduce_d(float4 p) {
    #pragma unroll
    for (int m = 4; m <= 32; m <<= 1) {
        p.x += __shfl_xor(p.x, m, 64);
        p.y += __shfl_xor(p.y, m, 64);
        p.z += __shfl_xor(p.z, m, 64);
        p.w += __shfl_xor(p.w, m, 64);
    }
    return p;
}
__device__ inline float reduce_d1(float v) {
    #pragma unroll
    for (int m = 4; m <= 32; m <<= 1) v += __shfl_xor(v, m, 64);
    return v;
}

__global__ __launch_bounds__(256) void hop1h_kernel(
    const float* __restrict__ Q, const _Float16* __restrict__ K0, const float* __restrict__ V,
    const int* __restrict__ offsets, const int* __restrict__ csr,
    const float* __restrict__ gam,
    _Float16* __restrict__ M1, _Float16* __restrict__ K1, float* __restrict__ hidden,
    int N, int h)
{
    int lane = threadIdx.x & 63;
    int node = blockIdx.x * 4 + (threadIdx.x >> 6);
    if (node >= N) return;
    int d = lane >> 2, c0 = (lane & 3) * 4;
    const _Float16* Kb = K0 + h * 16 + d;
    const float* Vb = V + h * CC + c0;
    float4 acc = make_float4(0.f, 0.f, 0.f, 0.f);
    float kacc = 0.f;
    int beg = offsets[node], end = offsets[node + 1];
    for (int t = beg; t < end; ++t) {
        int s = csr[t];
        float kv = (float)Kb[(size_t)s * 64];
        float4 v4 = *(const float4*)(Vb + (size_t)s * HID);
        kacc += kv;
        acc.x += kv * v4.x; acc.y += kv * v4.y;
        acc.z += kv * v4.z; acc.w += kv * v4.w;
    }
    half4 st = { (_Float16)acc.x, (_Float16)acc.y, (_Float16)acc.z, (_Float16)acc.w };
    *(half4*)(M1 + (size_t)node * 256 + lane * 4) = st;
    if ((lane & 3) == 0) K1[(size_t)node * 64 + h * 16 + d] = (_Float16)kacc;
    float qd = Q[(size_t)node * 64 + h * 16 + d];
    float4 pr = make_float4(qd * acc.x, qd * acc.y, qd * acc.z, qd * acc.w);
    pr = reduce_d(pr);
    float den = reduce_d1(qd * kacc) + CSTE;
    if (lane < 4) {
        float g = gam[h * 4 + 1] / den;
        float4* hp = (float4*)(hidden + (size_t)node * 64 + h * CC);
        float4 cur = hp[lane];
        cur.x += g * pr.x; cur.y += g * pr.y; cur.z += g * pr.z; cur.w += g * pr.w;
        hp[lane] = cur;
    }
}

__global__ __launch_bounds__(256) void hop23h_kernel(
    const float* __restrict__ Q, const _Float16* __restrict__ Mprev,
    const _Float16* __restrict__ Kprev,
    const int* __restrict__ offsets, const int* __restrict__ csr,
    const float* __restrict__ gam,
    _Float16* __restrict__ Mnext, _Float16* __restrict__ Knext, float* __restrict__ hidden,
    int N, int h, int hop)
{
    int lane = threadIdx.x & 63;
    int node = blockIdx.x * 4 + (threadIdx.x >> 6);
    if (node >= N) return;
    int d = lane >> 2;
    const _Float16* Kb = Kprev + h * 16 + d;
    float4 acc = make_float4(0.f, 0.f, 0.f, 0.f);
    float kacc = 0.f;
    int beg = offsets[node], end = offsets[node + 1];
    for (int t = beg; t < end; ++t) {
        int s = csr[t];
        half4 m = *(const half4*)(Mprev + (size_t)s * 256 + lane * 4);
        kacc += (float)Kb[(size_t)s * 64];
        acc.x += (float)m.x; acc.y += (float)m.y;
        acc.z += (float)m.z; acc.w += (float)m.w;
    }
    if (Mnext) {
        half4 st = { (_Float16)acc.x, (_Float16)acc.y, (_Float16)acc.z, (_Float16)acc.w };
        *(half4*)(Mnext + (size_t)node * 256 + lane * 4) = st;
        if ((lane & 3) == 0) Knext[(size_t)node * 64 + h * 16 + d] = (_Float16)kacc;
    }
    float qd = Q[(size_t)node * 64 + h * 16 + d];
    float4 pr = make_float4(qd * acc.x, qd * acc.y, qd * acc.z, qd * acc.w);
    pr = reduce_d(pr);
    float den = reduce_d1(qd * kacc) + CSTE;
    if (lane < 4) {
        float g = gam[h * 4 + hop] / den;
        float4* hp = (float4*)(hidden + (size_t)node * 64 + h * CC);
        float4 cur = hp[lane];
        cur.x += g * pr.x; cur.y += g * pr.y; cur.z += g * pr.z; cur.w += g * pr.w;
        hp[lane] = cur;
    }
}

// ---------------- output projection ----------------
__global__ __launch_bounds__(256) void out_kernel(
    const float* __restrict__ hidden, const float* __restrict__ Wo,
    const float* __restrict__ bo, float* __restrict__ out, int N)
{
    __shared__ float wo[HID * CC];
    for (int i = threadIdx.x; i < HID * CC; i += 256) wo[i] = Wo[i];
    __syncthreads();
    int idx = blockIdx.x * 256 + threadIdx.x;
    int n = idx >> 4, c = idx & 15;
    if (n >= N) return;
    float acc = bo[c];
    const float4* hp4 = (const float4*)(hidden + (size_t)n * HID);
    #pragma unroll
    for (int j4 = 0; j4 < 16; ++j4) {
        float4 hv = hp4[j4];
        acc += hv.x * wo[(4 * j4 + 0) * CC + c] + hv.y * wo[(4 * j4 + 1) * CC + c]
             + hv.z * wo[(4 * j4 + 2) * CC + c] + hv.w * wo[(4 * j4 + 3) * CC + c];
    }
    out[(size_t)n * CC + c] = acc;
}

extern "C" void kernel_launch(void* const* d_in, const int* in_sizes, int n_in,
                              void* d_out, int out_size, void* d_ws, size_t ws_size,
                              hipStream_t stream) {
    const float* x       = (const float*)d_in[0];
    const int*   ei      = (const int*)  d_in[1];
    const float* Wi      = (const float*)d_in[2];
    const float* bi      = (const float*)d_in[3];
    const float* Wq      = (const float*)d_in[4];
    const float* bq      = (const float*)d_in[5];
    const float* Wk      = (const float*)d_in[6];
    const float* bk      = (const float*)d_in[7];
    const float* Wv      = (const float*)d_in[8];
    const float* bv      = (const float*)d_in[9];
    const float* Wo      = (const float*)d_in[10];
    const float* bo      = (const float*)d_in[11];
    const float* hopwise = (const float*)d_in[12];
    const float* temp    = (const float*)d_in[13];

    const int N = in_sizes[0] / F_IN;
    const int E = in_sizes[1] / 2;

    char* ws = (char*)d_ws;
    size_t off = 0;
    auto take = [&](size_t bytes) -> char* {
        char* p = ws + off;
        off += (bytes + 255) & ~(size_t)255;
        return p;
    };
    float*        Q      = (float*)take((size_t)N * 64 * 4);
    float*        V      = (float*)take((size_t)N * 64 * 4);
    unsigned int* V2     = (unsigned int*)take((size_t)N * 32 * 4);
    float*        hidden = (float*)take((size_t)N * 64 * 4);
    _Float16*     K0     = (_Float16*)take((size_t)N * 64 * 2);
    _Float16*     K1     = (_Float16*)take((size_t)N * 64 * 2);
    _Float16*     K2     = (_Float16*)take((size_t)N * 64 * 2);
    float*        gam    = (float*)take(64);
    int*          degcur = (int*)  take((size_t)2 * N * 4);   // deg | cursor
    int*          offs   = (int*)  take((size_t)(N + 1) * 4);
    int*          csr    = (int*)  take((size_t)E * 4);
    int           nb     = (N + 4095) / 4096;
    int*          bsum   = (int*)  take((size_t)nb * 4);
    int*          bbase  = (int*)  take((size_t)nb * 4);

    // fast path needs 2 × all-head fp8 M buffers (N*1024 bytes each)
    size_t fast_need = off + 2 * (((size_t)N * 1024 + 255) & ~(size_t)255) + 4096;
    bool fast = (ws_size >= fast_need);

    int* deg    = degcur;
    int* cursor = degcur + N;

    hipMemsetAsync(degcur, 0, (size_t)2 * N * 4, stream);

    gamma_kernel<<<1, 64, 0, stream>>>(hopwise, temp, gam);

    int eb = (E + 255) / 256;
    count_kernel<<<eb, 256, 0, stream>>>(ei, deg, E);
    scan_a<<<nb, 1024, 0, stream>>>(deg, offs, bsum, N);
    scan_b<<<1, 64, 0, stream>>>(bsum, bbase, offs, nb, N);
    scan_c<<<(N + 255) / 256, 256, 0, stream>>>(offs, bbase, N);
    scatter_kernel<<<eb, 256, 0, stream>>>(ei, offs, cursor, csr, E);

    int qb = (N + 63) / 64;
    qkv_mfma<<<qb, 256, 0, stream>>>(x, Wi, bi, Wq, bq, Wk, bk, Wv, bv,
                                     gam, Q, K0, V, V2, hidden, N);

    int nb4 = (N + 3) / 4;
    if (fast) {
        uint4* M1 = (uint4*)take((size_t)N * 1024);
        uint4* M2 = (uint4*)take((size_t)N * 1024);
        hop1_all<<<nb4, 256, 0, stream>>>(Q, K0, V2, offs, csr, gam, M1, K1, hidden, N);
        hop23_all<true ><<<nb4, 256, 0, stream>>>(Q, M1, K1, offs, csr, gam,
                                                  M2, K2, hidden, N, 2);
        hop23_all<false><<<nb4, 256, 0, stream>>>(Q, M2, K2, offs, csr, gam,
                                                  (uint4*)nullptr, (_Float16*)nullptr,
                                                  hidden, N, 3);
    } else {
        _Float16* M1 = (_Float16*)take((size_t)N * 256 * 2);
        _Float16* M2 = (_Float16*)take((size_t)N * 256 * 2);
        for (int h = 0; h < NH; ++h) {
            hop1h_kernel<<<nb4, 256, 0, stream>>>(Q, K0, V, offs, csr, gam,
                                                  M1, K1, hidden, N, h);
            hop23h_kernel<<<nb4, 256, 0, stream>>>(Q, M1, K1, offs, csr, gam,
                                                   M2, K2, hidden, N, h, 2);
            hop23h_kernel<<<nb4, 256, 0, stream>>>(Q, M2, K2, offs, csr, gam,
                                                   (_Float16*)nullptr, (_Float16*)nullptr,
                                                   hidden, N, h, 3);
        }
    }

    int ob = (N * CC + 255) / 256;
    out_kernel<<<ob, 256, 0, stream>>>(hidden, Wo, bo, (float*)d_out, N);
}

// Round 8
// 374.162 us; speedup vs baseline: 1.5686x; 1.0415x over previous
//
#include <hip/hip_runtime.h>
#include <math.h>

#define F_IN 128
#define HID  64
#define NH   4
#define DD   16
#define CC   16
#define CSTE 1e-5f

typedef _Float16 h2    __attribute__((ext_vector_type(2)));
typedef float    f2    __attribute__((ext_vector_type(2)));
typedef short    short8 __attribute__((ext_vector_type(8)));
typedef float    f4v   __attribute__((ext_vector_type(4)));

// LDS strides (elements) — padded so b128 frag reads are ≤2-way bank conflicts
#define WIT_LD 136   // 128 + 8
#define W2T_LD 72    // 64 + 8
#define H_LD   72

__device__ __forceinline__ unsigned short bf16r(float f) {
    unsigned int u = __builtin_bit_cast(unsigned int, f);
    unsigned int r = (u + 0x7FFFu + ((u >> 16) & 1u)) >> 16;
    return (unsigned short)r;
}

// ---------------- fp8 helpers (OCP e4m3 via hw cvt) ----------------
__device__ __forceinline__ void fp8x16_add(const uint4 m, float* u) {
    const unsigned int w[4] = {m.x, m.y, m.z, m.w};
    #pragma unroll
    for (int q = 0; q < 4; ++q) {
        f2 lo = __builtin_amdgcn_cvt_pk_f32_fp8((int)w[q], false);
        f2 hi = __builtin_amdgcn_cvt_pk_f32_fp8((int)w[q], true);
        u[4 * q + 0] += lo.x; u[4 * q + 1] += lo.y;
        u[4 * q + 2] += hi.x; u[4 * q + 3] += hi.y;
    }
}
__device__ __forceinline__ uint4 fp8x16_pack(const float* u) {
    uint4 r;
    int w;
    w = __builtin_amdgcn_cvt_pk_fp8_f32(u[0],  u[1],  0, false);
    w = __builtin_amdgcn_cvt_pk_fp8_f32(u[2],  u[3],  w, true);
    r.x = (unsigned int)w;
    w = __builtin_amdgcn_cvt_pk_fp8_f32(u[4],  u[5],  0, false);
    w = __builtin_amdgcn_cvt_pk_fp8_f32(u[6],  u[7],  w, true);
    r.y = (unsigned int)w;
    w = __builtin_amdgcn_cvt_pk_fp8_f32(u[8],  u[9],  0, false);
    w = __builtin_amdgcn_cvt_pk_fp8_f32(u[10], u[11], w, true);
    r.z = (unsigned int)w;
    w = __builtin_amdgcn_cvt_pk_fp8_f32(u[12], u[13], 0, false);
    w = __builtin_amdgcn_cvt_pk_fp8_f32(u[14], u[15], w, true);
    r.w = (unsigned int)w;
    return r;
}
__device__ __forceinline__ float fp8_to_f32(unsigned char b) {
    f2 v = __builtin_amdgcn_cvt_pk_f32_fp8((int)(unsigned int)b, false);
    return v.x;
}
__device__ __forceinline__ unsigned char f32_to_fp8(float f) {
    int w = __builtin_amdgcn_cvt_pk_fp8_f32(f, f, 0, false);
    return (unsigned char)(w & 0xff);
}

// ---------------- gamma precompute (16 floats) ----------------
__global__ void gamma_kernel(const float* __restrict__ hopwise,
                             const float* __restrict__ temp,
                             float* __restrict__ gam) {
    if (threadIdx.x == 0 && blockIdx.x == 0) {
        for (int h = 0; h < NH; ++h) gam[h * 4 + 0] = temp[h * 4 + 0]; // hop0: raw temp
        for (int hop = 1; hop <= 3; ++hop) {
            float m = -1e30f;
            for (int h = 0; h < NH; ++h) m = fmaxf(m, temp[h * 4 + hop]);
            float e[NH], s = 0.f;
            for (int h = 0; h < NH; ++h) { e[h] = expf(temp[h * 4 + hop] - m); s += e[h]; }
            for (int h = 0; h < NH; ++h) gam[h * 4 + hop] = hopwise[hop] * e[h] / s;
        }
    }
}

// ---------------- CSR build ----------------
__global__ void count_kernel(const int* __restrict__ ei, int* __restrict__ deg, int E) {
    int e = blockIdx.x * blockDim.x + threadIdx.x;
    if (e < E) atomicAdd(&deg[ei[E + e]], 1);   // dst = ei[1][e]
}

__global__ __launch_bounds__(1024) void scan_a(const int* __restrict__ deg,
                                               int* __restrict__ offsets,
                                               int* __restrict__ bsum, int N) {
    __shared__ int wsum[16], woff[16];
    int lane = threadIdx.x & 63, w = threadIdx.x >> 6;
    int i0 = blockIdx.x * 4096 + (int)threadIdx.x * 4;
    int d0 = (i0 + 0 < N) ? deg[i0 + 0] : 0;
    int d1 = (i0 + 1 < N) ? deg[i0 + 1] : 0;
    int d2 = (i0 + 2 < N) ? deg[i0 + 2] : 0;
    int d3 = (i0 + 3 < N) ? deg[i0 + 3] : 0;
    int tsum = d0 + d1 + d2 + d3;
    int incl = tsum;
    #pragma unroll
    for (int m = 1; m < 64; m <<= 1) {
        int t = __shfl_up(incl, m, 64);
        if (lane >= m) incl += t;
    }
    if (lane == 63) wsum[w] = incl;
    __syncthreads();
    if (threadIdx.x == 0) {
        int r = 0;
        for (int k = 0; k < 16; ++k) { int t = wsum[k]; woff[k] = r; r += t; }
        bsum[blockIdx.x] = r;
    }
    __syncthreads();
    int excl = woff[w] + incl - tsum;
    if (i0 + 0 < N) offsets[i0 + 0] = excl;
    if (i0 + 1 < N) offsets[i0 + 1] = excl + d0;
    if (i0 + 2 < N) offsets[i0 + 2] = excl + d0 + d1;
    if (i0 + 3 < N) offsets[i0 + 3] = excl + d0 + d1 + d2;
}

__global__ void scan_b(int* __restrict__ bsum, int* __restrict__ bbase,
                       int* __restrict__ offsets, int nb, int N) {
    if (threadIdx.x == 0) {
        int r = 0;
        for (int i = 0; i < nb; ++i) { int t = bsum[i]; bbase[i] = r; r += t; }
        offsets[N] = r;
    }
}

__global__ void scan_c(int* __restrict__ offsets, const int* __restrict__ bbase, int N) {
    int i = blockIdx.x * blockDim.x + threadIdx.x;
    if (i < N) offsets[i] += bbase[i >> 12];
}

__global__ void scatter_kernel(const int* __restrict__ ei, const int* __restrict__ offsets,
                               int* __restrict__ cursor, int* __restrict__ csr, int E) {
    int e = blockIdx.x * blockDim.x + threadIdx.x;
    if (e < E) {
        int src = ei[e];
        int dst = ei[E + e];
        int pos = atomicAdd(&cursor[dst], 1);
        csr[offsets[dst] + pos] = src;
    }
}

// ---------------- MFMA QKV: 64 nodes/block, 4 waves ----------------
__global__ __launch_bounds__(256) void qkv_mfma(
    const float* __restrict__ x,
    const float* __restrict__ Wi, const float* __restrict__ bi,
    const float* __restrict__ Wq, const float* __restrict__ bq,
    const float* __restrict__ Wk, const float* __restrict__ bk,
    const float* __restrict__ Wv, const float* __restrict__ bv,
    const float* __restrict__ gam,
    float* __restrict__ Q, unsigned char* __restrict__ K0,
    _Float16* __restrict__ Vh, float* __restrict__ hidden, int N)
{
    __shared__ unsigned short wit[64 * WIT_LD];    // Wi^T  [n][k]
    __shared__ unsigned short w2t[192 * W2T_LD];   // W2^T  [n][k] (Wq|Wk|Wv cols)
    __shared__ unsigned short hlds[64 * H_LD];     // h     [node][k]
    int t = threadIdx.x;
    #pragma unroll
    for (int i = 0; i < 32; ++i) {
        int g = t + i * 256;                       // 8192 = 128*64
        wit[(g & 63) * WIT_LD + (g >> 6)] = bf16r(Wi[g]);
    }
    #pragma unroll
    for (int i = 0; i < 16; ++i) {
        int g = t + i * 256;                       // 4096 = 64*64
        int k = g >> 6, n = g & 63;
        w2t[(n      ) * W2T_LD + k] = bf16r(Wq[g]);
        w2t[(n +  64) * W2T_LD + k] = bf16r(Wk[g]);
        w2t[(n + 128) * W2T_LD + k] = bf16r(Wv[g]);
    }
    __syncthreads();

    int lane = t & 63, w = t >> 6;
    int p = lane & 15, quad = lane >> 4;
    int mbase = blockIdx.x * 64 + w * 16;

    // ---- stage 1: h = relu(x@Wi + bi) ----
    short8 afrag[4];
    {
        int node = mbase + p;
        if (node >= N) node = N - 1;               // clamped read; stores guarded
        const float* xr = x + (size_t)node * F_IN + quad * 8;
        #pragma unroll
        for (int ks = 0; ks < 4; ++ks) {
            float4 a0 = *(const float4*)(xr + ks * 32);
            float4 a1 = *(const float4*)(xr + ks * 32 + 4);
            short8 f;
            f[0] = bf16r(a0.x); f[1] = bf16r(a0.y); f[2] = bf16r(a0.z); f[3] = bf16r(a0.w);
            f[4] = bf16r(a1.x); f[5] = bf16r(a1.y); f[6] = bf16r(a1.z); f[7] = bf16r(a1.w);
            afrag[ks] = f;
        }
    }
    #pragma unroll
    for (int nt = 0; nt < 4; ++nt) {
        f4v acc = {0.f, 0.f, 0.f, 0.f};
        #pragma unroll
        for (int ks = 0; ks < 4; ++ks) {
            short8 b = *(const short8*)&wit[(nt * 16 + p) * WIT_LD + ks * 32 + quad * 8];
            acc = __builtin_amdgcn_mfma_f32_16x16x32_bf16(afrag[ks], b, acc, 0, 0, 0);
        }
        float bb = bi[nt * 16 + p];
        #pragma unroll
        for (int r = 0; r < 4; ++r) {
            float hv = fmaxf(acc[r] + bb, 0.f);
            hlds[(w * 16 + quad * 4 + r) * H_LD + nt * 16 + p] = bf16r(hv);
        }
    }
    __syncthreads();

    // ---- stage 2: [Q|K|V] = h @ W2 + b ----
    short8 ha0 = *(const short8*)&hlds[(w * 16 + p) * H_LD + quad * 8];
    short8 ha1 = *(const short8*)&hlds[(w * 16 + p) * H_LD + 32 + quad * 8];
    int node_r = mbase + quad * 4;
    #pragma unroll
    for (int nt = 0; nt < 12; ++nt) {
        f4v acc = {0.f, 0.f, 0.f, 0.f};
        short8 b0 = *(const short8*)&w2t[(nt * 16 + p) * W2T_LD + quad * 8];
        short8 b1 = *(const short8*)&w2t[(nt * 16 + p) * W2T_LD + 32 + quad * 8];
        acc = __builtin_amdgcn_mfma_f32_16x16x32_bf16(ha0, b0, acc, 0, 0, 0);
        acc = __builtin_amdgcn_mfma_f32_16x16x32_bf16(ha1, b1, acc, 0, 0, 0);
        int col = nt * 16 + p;
        #pragma unroll
        for (int r = 0; r < 4; ++r) {
            int node = node_r + r;
            if (node >= N) continue;
            float v = acc[r];
            if (col < 64) {
                v += bq[col];
                Q[(size_t)node * 64 + col] = (v > 0.f) ? (1.f + v) : __expf(v);
            } else if (col < 128) {
                int c = col - 64;
                v += bk[c];
                float kv = (v > 0.f) ? (1.f + v) : __expf(v);
                K0[(size_t)node * 64 + c] = f32_to_fp8(kv);
            } else {
                int c = col - 128;
                v += bv[c];
                Vh[(size_t)node * 64 + c] = (_Float16)v;
                hidden[(size_t)node * 64 + c] = v * gam[(c >> 4) * 4];
            }
        }
    }
}

// M layout: per node 64 uint4 (1024 fp8), NATURAL columns:
// lane (h*16+p), byte j holds M[h][d=p][c=j].

// ---------------- epilogue: Q-scale, reduce-scatter over d (natural layout) ----------------
// lane (h,p): u[c] = qd * M[h][p][c]; afterwards lane holds column c=p total in u[0].
__device__ __forceinline__ void hop_epilogue(
    float* u, float qd, float kacc, const float* gam,
    float* __restrict__ hidden, int node, int lane, int hop)
{
    int p = lane & 15;
    #pragma unroll
    for (int j = 0; j < 16; ++j) u[j] *= qd;
    #pragma unroll
    for (int k = 0; k < 4; ++k) {
        const int m = 1 << k;
        bool bit = (p >> k) & 1;
        const int n = 8 >> k;
        #pragma unroll
        for (int j = 0; j < n; ++j) {
            float give = bit ? u[2 * j]     : u[2 * j + 1];
            float keep = bit ? u[2 * j + 1] : u[2 * j];
            float got  = __shfl_xor(give, m, 64);
            u[j] = keep + got;
        }
    }
    float kq = qd * kacc;
    kq += __shfl_xor(kq, 1, 64);
    kq += __shfl_xor(kq, 2, 64);
    kq += __shfl_xor(kq, 4, 64);
    kq += __shfl_xor(kq, 8, 64);
    float g = gam[(lane >> 4) * 4 + hop] / (kq + CSTE);
    hidden[(size_t)node * 64 + lane] += g * u[0];
}

// ---------------- hop 1: M1 = A (K ⊗ V) fp8, K1 = A K0 fp8 ----------------
// lane (h,p): accumulates k[s][h,p] * V[s][h][c] for c=0..15 as 8 packed half2.
__global__ __launch_bounds__(256) void hop1_all(
    const float* __restrict__ Q, const unsigned char* __restrict__ K0,
    const _Float16* __restrict__ Vh,
    const int* __restrict__ offsets, const int* __restrict__ csr,
    const float* __restrict__ gam,
    uint4* __restrict__ M1, unsigned char* __restrict__ K1,
    float* __restrict__ hidden, int N)
{
    int lane = threadIdx.x & 63;
    int node = blockIdx.x * 4 + (threadIdx.x >> 6);
    if (node >= N) return;
    int h = lane >> 4;
    h2 u16[8];
    #pragma unroll
    for (int j = 0; j < 8; ++j) u16[j] = h2{(_Float16)0.f, (_Float16)0.f};
    float kacc = 0.f;
    int beg = offsets[node], end = offsets[node + 1];
    int t = beg;
    for (; t + 1 < end; t += 2) {
        int s0 = csr[t], s1 = csr[t + 1];
        const uint4* v0p = (const uint4*)(Vh + (size_t)s0 * 64 + h * 16);
        const uint4* v1p = (const uint4*)(Vh + (size_t)s1 * 64 + h * 16);
        uint4 a0 = v0p[0], a1 = v0p[1];
        uint4 b0 = v1p[0], b1 = v1p[1];
        float k0 = fp8_to_f32(K0[(size_t)s0 * 64 + lane]);
        float k1 = fp8_to_f32(K0[(size_t)s1 * 64 + lane]);
        kacc += k0 + k1;
        _Float16 k0h = (_Float16)k0, k1h = (_Float16)k1;
        h2 k02 = {k0h, k0h}, k12 = {k1h, k1h};
        const unsigned int aw[8] = {a0.x, a0.y, a0.z, a0.w, a1.x, a1.y, a1.z, a1.w};
        const unsigned int bw[8] = {b0.x, b0.y, b0.z, b0.w, b1.x, b1.y, b1.z, b1.w};
        #pragma unroll
        for (int j = 0; j < 8; ++j) {
            u16[j] += k02 * __builtin_bit_cast(h2, aw[j]);
            u16[j] += k12 * __builtin_bit_cast(h2, bw[j]);
        }
    }
    for (; t < end; ++t) {
        int s = csr[t];
        const uint4* vp = (const uint4*)(Vh + (size_t)s * 64 + h * 16);
        uint4 a0 = vp[0], a1 = vp[1];
        float kk = fp8_to_f32(K0[(size_t)s * 64 + lane]);
        kacc += kk;
        _Float16 kh = (_Float16)kk;
        h2 k2 = {kh, kh};
        const unsigned int aw[8] = {a0.x, a0.y, a0.z, a0.w, a1.x, a1.y, a1.z, a1.w};
        #pragma unroll
        for (int j = 0; j < 8; ++j)
            u16[j] += k2 * __builtin_bit_cast(h2, aw[j]);
    }
    float u[16];
    #pragma unroll
    for (int j = 0; j < 8; ++j) { u[2 * j] = (float)u16[j].x; u[2 * j + 1] = (float)u16[j].y; }
    M1[(size_t)node * 64 + lane] = fp8x16_pack(u);
    K1[(size_t)node * 64 + lane] = f32_to_fp8(kacc);
    float qd = Q[(size_t)node * 64 + lane];
    hop_epilogue(u, qd, kacc, gam, hidden, node, lane, 1);
}

// ---------------- hops 2/3: single pass, fp8 M + fp8 K gather ----------------
template<bool STORE>
__global__ __launch_bounds__(256) void hop23_all(
    const float* __restrict__ Q, const uint4* __restrict__ Mprev,
    const unsigned char* __restrict__ Kprev,
    const int* __restrict__ offsets, const int* __restrict__ csr,
    const float* __restrict__ gam,
    uint4* __restrict__ Mnext, unsigned char* __restrict__ Knext,
    float* __restrict__ hidden, int N, int hop)
{
    int lane = threadIdx.x & 63;
    int node = blockIdx.x * 4 + (threadIdx.x >> 6);
    if (node >= N) return;
    const uint4* Mb = Mprev + lane;
    float u[16];
    #pragma unroll
    for (int j = 0; j < 16; ++j) u[j] = 0.f;
    float kacc = 0.f;
    int beg = offsets[node], end = offsets[node + 1];
    int t = beg;
    for (; t + 3 < end; t += 4) {
        int s0 = csr[t], s1 = csr[t + 1], s2 = csr[t + 2], s3 = csr[t + 3];
        uint4 m0 = Mb[(size_t)s0 * 64];
        uint4 m1 = Mb[(size_t)s1 * 64];
        uint4 m2 = Mb[(size_t)s2 * 64];
        uint4 m3 = Mb[(size_t)s3 * 64];
        kacc += (fp8_to_f32(Kprev[(size_t)s0 * 64 + lane]) + fp8_to_f32(Kprev[(size_t)s1 * 64 + lane]))
              + (fp8_to_f32(Kprev[(size_t)s2 * 64 + lane]) + fp8_to_f32(Kprev[(size_t)s3 * 64 + lane]));
        fp8x16_add(m0, u);
        fp8x16_add(m1, u);
        fp8x16_add(m2, u);
        fp8x16_add(m3, u);
    }
    for (; t < end; ++t) {
        int s = csr[t];
        uint4 m = Mb[(size_t)s * 64];
        kacc += fp8_to_f32(Kprev[(size_t)s * 64 + lane]);
        fp8x16_add(m, u);
    }
    if (STORE) {
        Mnext[(size_t)node * 64 + lane] = fp8x16_pack(u);
        Knext[(size_t)node * 64 + lane] = f32_to_fp8(kacc);
    }
    float qd = Q[(size_t)node * 64 + lane];
    hop_epilogue(u, qd, kacc, gam, hidden, node, lane, hop);
}

// ---------------- output projection ----------------
__global__ __launch_bounds__(256) void out_kernel(
    const float* __restrict__ hidden, const float* __restrict__ Wo,
    const float* __restrict__ bo, float* __restrict__ out, int N)
{
    __shared__ float wo[HID * CC];
    for (int i = threadIdx.x; i < HID * CC; i += 256) wo[i] = Wo[i];
    __syncthreads();
    int idx = blockIdx.x * 256 + threadIdx.x;
    int n = idx >> 4, c = idx & 15;
    if (n >= N) return;
    float acc = bo[c];
    const float4* hp4 = (const float4*)(hidden + (size_t)n * HID);
    #pragma unroll
    for (int j4 = 0; j4 < 16; ++j4) {
        float4 hv = hp4[j4];
        acc += hv.x * wo[(4 * j4 + 0) * CC + c] + hv.y * wo[(4 * j4 + 1) * CC + c]
             + hv.z * wo[(4 * j4 + 2) * CC + c] + hv.w * wo[(4 * j4 + 3) * CC + c];
    }
    out[(size_t)n * CC + c] = acc;
}

extern "C" void kernel_launch(void* const* d_in, const int* in_sizes, int n_in,
                              void* d_out, int out_size, void* d_ws, size_t ws_size,
                              hipStream_t stream) {
    const float* x       = (const float*)d_in[0];
    const int*   ei      = (const int*)  d_in[1];
    const float* Wi      = (const float*)d_in[2];
    const float* bi      = (const float*)d_in[3];
    const float* Wq      = (const float*)d_in[4];
    const float* bq      = (const float*)d_in[5];
    const float* Wk      = (const float*)d_in[6];
    const float* bk      = (const float*)d_in[7];
    const float* Wv      = (const float*)d_in[8];
    const float* bv      = (const float*)d_in[9];
    const float* Wo      = (const float*)d_in[10];
    const float* bo      = (const float*)d_in[11];
    const float* hopwise = (const float*)d_in[12];
    const float* temp    = (const float*)d_in[13];

    const int N = in_sizes[0] / F_IN;
    const int E = in_sizes[1] / 2;

    char* ws = (char*)d_ws;
    size_t off = 0;
    auto take = [&](size_t bytes) -> char* {
        char* p = ws + off;
        off += (bytes + 255) & ~(size_t)255;
        return p;
    };
    float*         Q      = (float*)take((size_t)N * 64 * 4);
    _Float16*      Vh     = (_Float16*)take((size_t)N * 64 * 2);
    float*         hidden = (float*)take((size_t)N * 64 * 4);
    unsigned char* K0     = (unsigned char*)take((size_t)N * 64);
    unsigned char* K1     = (unsigned char*)take((size_t)N * 64);
    unsigned char* K2     = (unsigned char*)take((size_t)N * 64);
    float*         gam    = (float*)take(64);
    int*           degcur = (int*)  take((size_t)2 * N * 4);   // deg | cursor
    int*           offs   = (int*)  take((size_t)(N + 1) * 4);
    int*           csr    = (int*)  take((size_t)E * 4);
    int            nb     = (N + 4095) / 4096;
    int*           bsum   = (int*)  take((size_t)nb * 4);
    int*           bbase  = (int*)  take((size_t)nb * 4);
    uint4*         M1     = (uint4*)take((size_t)N * 1024);
    uint4*         M2     = (uint4*)take((size_t)N * 1024);

    int* deg    = degcur;
    int* cursor = degcur + N;

    hipMemsetAsync(degcur, 0, (size_t)2 * N * 4, stream);

    gamma_kernel<<<1, 64, 0, stream>>>(hopwise, temp, gam);

    int eb = (E + 255) / 256;
    count_kernel<<<eb, 256, 0, stream>>>(ei, deg, E);
    scan_a<<<nb, 1024, 0, stream>>>(deg, offs, bsum, N);
    scan_b<<<1, 64, 0, stream>>>(bsum, bbase, offs, nb, N);
    scan_c<<<(N + 255) / 256, 256, 0, stream>>>(offs, bbase, N);
    scatter_kernel<<<eb, 256, 0, stream>>>(ei, offs, cursor, csr, E);

    int qb = (N + 63) / 64;
    qkv_mfma<<<qb, 256, 0, stream>>>(x, Wi, bi, Wq, bq, Wk, bk, Wv, bv,
                                     gam, Q, K0, Vh, hidden, N);

    int nb4 = (N + 3) / 4;
    hop1_all<<<nb4, 256, 0, stream>>>(Q, K0, Vh, offs, csr, gam, M1, K1, hidden, N);
    hop23_all<true ><<<nb4, 256, 0, stream>>>(Q, M1, K1, offs, csr, gam,
                                              M2, K2, hidden, N, 2);
    hop23_all<false><<<nb4, 256, 0, stream>>>(Q, M2, K2, offs, csr, gam,
                                              (uint4*)nullptr, (unsigned char*)nullptr,
                                              hidden, N, 3);

    int ob = (N * CC + 255) / 256;
    out_kernel<<<ob, 256, 0, stream>>>(hidden, Wo, bo, (float*)d_out, N);
}

// Round 9
// 320.148 us; speedup vs baseline: 1.8332x; 1.1687x over previous
//
#include <hip/hip_runtime.h>
#include <math.h>

#define F_IN 128
#define HID  64
#define NH   4
#define DD   16
#define CC   16
#define CSTE 1e-5f

typedef _Float16 h2     __attribute__((ext_vector_type(2)));
typedef float    f2     __attribute__((ext_vector_type(2)));
typedef short    short8 __attribute__((ext_vector_type(8)));
typedef float    f4v    __attribute__((ext_vector_type(4)));

// LDS strides (elements) — padded so b128 frag reads are ≤2-way bank conflicts
#define WIT_LD 136
#define W2T_LD 72
#define H_LD   72

__device__ __forceinline__ unsigned short bf16r(float f) {
    unsigned int u = __builtin_bit_cast(unsigned int, f);
    unsigned int r = (u + 0x7FFFu + ((u >> 16) & 1u)) >> 16;
    return (unsigned short)r;
}

// ---------------- fp8 scalar helpers (OCP e4m3 via hw cvt) ----------------
__device__ __forceinline__ float fp8_to_f32(unsigned int b) {
    f2 v = __builtin_amdgcn_cvt_pk_f32_fp8((int)b, false);
    return v.x;
}
__device__ __forceinline__ unsigned char f32_to_fp8(float f) {
    int w = __builtin_amdgcn_cvt_pk_fp8_f32(f, f, 0, false);
    return (unsigned char)(w & 0xff);
}

// ---------------- fp4 e2m1 16-value pack/unpack ----------------
#if __has_builtin(__builtin_amdgcn_cvt_scalef32_pk_f32_fp4) && __has_builtin(__builtin_amdgcn_cvt_scalef32_pk_fp4_f32)
#define HAS_FP4 1
#endif

#ifndef HAS_FP4
__device__ __forceinline__ float fp4_dec1(unsigned int n) {
    unsigned int e = (n >> 1) & 3u, m = n & 1u;
    float mag = (e == 0) ? 0.5f * (float)m
                         : (float)(1u << (e - 1)) * (1.0f + 0.5f * (float)m);
    return (n & 8u) ? -mag : mag;
}
__device__ __forceinline__ unsigned int fp4_enc1(float f) {
    unsigned int s = (f < 0.f) ? 8u : 0u;
    float a = fabsf(f);
    unsigned int m;
    if      (a < 0.25f) m = 0u;
    else if (a < 0.75f) m = 1u;
    else if (a < 1.25f) m = 2u;
    else if (a < 1.75f) m = 3u;
    else if (a < 2.5f)  m = 4u;
    else if (a < 3.5f)  m = 5u;
    else if (a < 5.0f)  m = 6u;
    else                m = 7u;
    return s | m;
}
#endif

__device__ __forceinline__ void fp4x16_dec(uint2 w, float* v) {
#ifdef HAS_FP4
    f2 r;
    r = __builtin_amdgcn_cvt_scalef32_pk_f32_fp4(w.x, 1.0f, 0); v[0]  = r.x; v[1]  = r.y;
    r = __builtin_amdgcn_cvt_scalef32_pk_f32_fp4(w.x, 1.0f, 1); v[2]  = r.x; v[3]  = r.y;
    r = __builtin_amdgcn_cvt_scalef32_pk_f32_fp4(w.x, 1.0f, 2); v[4]  = r.x; v[5]  = r.y;
    r = __builtin_amdgcn_cvt_scalef32_pk_f32_fp4(w.x, 1.0f, 3); v[6]  = r.x; v[7]  = r.y;
    r = __builtin_amdgcn_cvt_scalef32_pk_f32_fp4(w.y, 1.0f, 0); v[8]  = r.x; v[9]  = r.y;
    r = __builtin_amdgcn_cvt_scalef32_pk_f32_fp4(w.y, 1.0f, 1); v[10] = r.x; v[11] = r.y;
    r = __builtin_amdgcn_cvt_scalef32_pk_f32_fp4(w.y, 1.0f, 2); v[12] = r.x; v[13] = r.y;
    r = __builtin_amdgcn_cvt_scalef32_pk_f32_fp4(w.y, 1.0f, 3); v[14] = r.x; v[15] = r.y;
#else
    #pragma unroll
    for (int j = 0; j < 8; ++j) {
        v[j]     = fp4_dec1((w.x >> (4 * j)) & 0xFu);
        v[8 + j] = fp4_dec1((w.y >> (4 * j)) & 0xFu);
    }
#endif
}

__device__ __forceinline__ uint2 fp4x16_enc(const float* v) {
#ifdef HAS_FP4
    unsigned int a = 0u, b = 0u;
    a = __builtin_amdgcn_cvt_scalef32_pk_fp4_f32(a, v[0],  v[1],  1.0f, 0);
    a = __builtin_amdgcn_cvt_scalef32_pk_fp4_f32(a, v[2],  v[3],  1.0f, 1);
    a = __builtin_amdgcn_cvt_scalef32_pk_fp4_f32(a, v[4],  v[5],  1.0f, 2);
    a = __builtin_amdgcn_cvt_scalef32_pk_fp4_f32(a, v[6],  v[7],  1.0f, 3);
    b = __builtin_amdgcn_cvt_scalef32_pk_fp4_f32(b, v[8],  v[9],  1.0f, 0);
    b = __builtin_amdgcn_cvt_scalef32_pk_fp4_f32(b, v[10], v[11], 1.0f, 1);
    b = __builtin_amdgcn_cvt_scalef32_pk_fp4_f32(b, v[12], v[13], 1.0f, 2);
    b = __builtin_amdgcn_cvt_scalef32_pk_fp4_f32(b, v[14], v[15], 1.0f, 3);
    return {a, b};
#else
    unsigned int a = 0u, b = 0u;
    #pragma unroll
    for (int j = 0; j < 8; ++j) {
        a |= fp4_enc1(v[j])     << (4 * j);
        b |= fp4_enc1(v[8 + j]) << (4 * j);
    }
    return {a, b};
#endif
}

// store one M row: per-row fp8 scale (s8), fp4 payload, K packed with scale
__device__ __forceinline__ void store_m_row(
    uint2* __restrict__ Mout, unsigned short* __restrict__ SKout,
    int node, int lane, const float* u, float kacc)
{
    float rm = 0.f;
    #pragma unroll
    for (int j = 0; j < 16; ++j) rm = fmaxf(rm, fabsf(u[j]));
    unsigned char s8 = f32_to_fp8(rm * (1.0f / 6.0f));
    float se = fp8_to_f32((unsigned int)s8);
    float invs = (se > 0.f) ? (1.0f / se) : 0.f;
    float tq[16];
    #pragma unroll
    for (int j = 0; j < 16; ++j) tq[j] = u[j] * invs;
    Mout[(size_t)node * 64 + lane] = fp4x16_enc(tq);
    SKout[(size_t)node * 64 + lane] =
        (unsigned short)((unsigned short)s8 | ((unsigned short)f32_to_fp8(kacc) << 8));
}

// per-hop gamma (hop>=1): hopwise[hop] * softmax_over_heads(temp[:,hop])[h]
__device__ __forceinline__ float gamma_for(const float* __restrict__ temp,
                                           const float* __restrict__ hopwise,
                                           int h, int hop) {
    float t0 = temp[0 * 4 + hop], t1 = temp[1 * 4 + hop];
    float t2 = temp[2 * 4 + hop], t3 = temp[3 * 4 + hop];
    float mx = fmaxf(fmaxf(t0, t1), fmaxf(t2, t3));
    float e0 = __expf(t0 - mx), e1 = __expf(t1 - mx);
    float e2 = __expf(t2 - mx), e3 = __expf(t3 - mx);
    float ssum = e0 + e1 + e2 + e3;
    float eh = (h == 0) ? e0 : (h == 1) ? e1 : (h == 2) ? e2 : e3;
    return hopwise[hop] * eh / ssum;
}

// ---------------- CSR build ----------------
__global__ void count_kernel(const int* __restrict__ ei, int* __restrict__ deg, int E) {
    int e = blockIdx.x * blockDim.x + threadIdx.x;
    if (e < E) atomicAdd(&deg[ei[E + e]], 1);   // dst = ei[1][e]
}

__global__ __launch_bounds__(1024) void scan_a(const int* __restrict__ deg,
                                               int* __restrict__ offsets,
                                               int* __restrict__ bsum, int N) {
    __shared__ int wsum[16], woff[16];
    int lane = threadIdx.x & 63, w = threadIdx.x >> 6;
    int i0 = blockIdx.x * 4096 + (int)threadIdx.x * 4;
    int d0 = (i0 + 0 < N) ? deg[i0 + 0] : 0;
    int d1 = (i0 + 1 < N) ? deg[i0 + 1] : 0;
    int d2 = (i0 + 2 < N) ? deg[i0 + 2] : 0;
    int d3 = (i0 + 3 < N) ? deg[i0 + 3] : 0;
    int tsum = d0 + d1 + d2 + d3;
    int incl = tsum;
    #pragma unroll
    for (int m = 1; m < 64; m <<= 1) {
        int t = __shfl_up(incl, m, 64);
        if (lane >= m) incl += t;
    }
    if (lane == 63) wsum[w] = incl;
    __syncthreads();
    if (threadIdx.x == 0) {
        int r = 0;
        for (int k = 0; k < 16; ++k) { int t = wsum[k]; woff[k] = r; r += t; }
        bsum[blockIdx.x] = r;
    }
    __syncthreads();
    int excl = woff[w] + incl - tsum;
    if (i0 + 0 < N) offsets[i0 + 0] = excl;
    if (i0 + 1 < N) offsets[i0 + 1] = excl + d0;
    if (i0 + 2 < N) offsets[i0 + 2] = excl + d0 + d1;
    if (i0 + 3 < N) offsets[i0 + 3] = excl + d0 + d1 + d2;
}

// adds block bases (nb small) and writes offsets[N]
__global__ void scan_c(int* __restrict__ offsets, const int* __restrict__ bsum,
                       int nb, int N) {
    int i = blockIdx.x * blockDim.x + threadIdx.x;
    if (i < N) {
        int bkt = i >> 12;
        int base = 0;
        for (int b = 0; b < bkt; ++b) base += bsum[b];
        offsets[i] += base;
    }
    if (i == 0) {
        int tot = 0;
        for (int b = 0; b < nb; ++b) tot += bsum[b];
        offsets[N] = tot;
    }
}

__global__ void scatter_kernel(const int* __restrict__ ei, const int* __restrict__ offsets,
                               int* __restrict__ cursor, int* __restrict__ csr, int E) {
    int e = blockIdx.x * blockDim.x + threadIdx.x;
    if (e < E) {
        int src = ei[e];
        int dst = ei[E + e];
        int pos = atomicAdd(&cursor[dst], 1);
        csr[offsets[dst] + pos] = src;
    }
}

// ---------------- MFMA QKV: 64 nodes/block, 4 waves ----------------
__global__ __launch_bounds__(256) void qkv_mfma(
    const float* __restrict__ x,
    const float* __restrict__ Wi, const float* __restrict__ bi,
    const float* __restrict__ Wq, const float* __restrict__ bq,
    const float* __restrict__ Wk, const float* __restrict__ bk,
    const float* __restrict__ Wv, const float* __restrict__ bv,
    const float* __restrict__ temp,
    float* __restrict__ Q, unsigned char* __restrict__ K0,
    _Float16* __restrict__ Vh, float* __restrict__ hidden, int N)
{
    __shared__ unsigned short wit[64 * WIT_LD];    // Wi^T  [n][k]
    __shared__ unsigned short w2t[192 * W2T_LD];   // W2^T  [n][k] (Wq|Wk|Wv cols)
    __shared__ unsigned short hlds[64 * H_LD];     // h     [node][k]
    int t = threadIdx.x;
    #pragma unroll
    for (int i = 0; i < 32; ++i) {
        int g = t + i * 256;                       // 8192 = 128*64
        wit[(g & 63) * WIT_LD + (g >> 6)] = bf16r(Wi[g]);
    }
    #pragma unroll
    for (int i = 0; i < 16; ++i) {
        int g = t + i * 256;                       // 4096 = 64*64
        int k = g >> 6, n = g & 63;
        w2t[(n      ) * W2T_LD + k] = bf16r(Wq[g]);
        w2t[(n +  64) * W2T_LD + k] = bf16r(Wk[g]);
        w2t[(n + 128) * W2T_LD + k] = bf16r(Wv[g]);
    }
    __syncthreads();

    int lane = t & 63, w = t >> 6;
    int p = lane & 15, quad = lane >> 4;
    int mbase = blockIdx.x * 64 + w * 16;

    // ---- stage 1: h = relu(x@Wi + bi) ----
    short8 afrag[4];
    {
        int node = mbase + p;
        if (node >= N) node = N - 1;               // clamped read; stores guarded
        const float* xr = x + (size_t)node * F_IN + quad * 8;
        #pragma unroll
        for (int ks = 0; ks < 4; ++ks) {
            float4 a0 = *(const float4*)(xr + ks * 32);
            float4 a1 = *(const float4*)(xr + ks * 32 + 4);
            short8 f;
            f[0] = bf16r(a0.x); f[1] = bf16r(a0.y); f[2] = bf16r(a0.z); f[3] = bf16r(a0.w);
            f[4] = bf16r(a1.x); f[5] = bf16r(a1.y); f[6] = bf16r(a1.z); f[7] = bf16r(a1.w);
            afrag[ks] = f;
        }
    }
    #pragma unroll
    for (int nt = 0; nt < 4; ++nt) {
        f4v acc = {0.f, 0.f, 0.f, 0.f};
        #pragma unroll
        for (int ks = 0; ks < 4; ++ks) {
            short8 b = *(const short8*)&wit[(nt * 16 + p) * WIT_LD + ks * 32 + quad * 8];
            acc = __builtin_amdgcn_mfma_f32_16x16x32_bf16(afrag[ks], b, acc, 0, 0, 0);
        }
        float bb = bi[nt * 16 + p];
        #pragma unroll
        for (int r = 0; r < 4; ++r) {
            float hv = fmaxf(acc[r] + bb, 0.f);
            hlds[(w * 16 + quad * 4 + r) * H_LD + nt * 16 + p] = bf16r(hv);
        }
    }
    __syncthreads();

    // ---- stage 2: [Q|K|V] = h @ W2 + b ----
    short8 ha0 = *(const short8*)&hlds[(w * 16 + p) * H_LD + quad * 8];
    short8 ha1 = *(const short8*)&hlds[(w * 16 + p) * H_LD + 32 + quad * 8];
    int node_r = mbase + quad * 4;
    #pragma unroll
    for (int nt = 0; nt < 12; ++nt) {
        f4v acc = {0.f, 0.f, 0.f, 0.f};
        short8 b0 = *(const short8*)&w2t[(nt * 16 + p) * W2T_LD + quad * 8];
        short8 b1 = *(const short8*)&w2t[(nt * 16 + p) * W2T_LD + 32 + quad * 8];
        acc = __builtin_amdgcn_mfma_f32_16x16x32_bf16(ha0, b0, acc, 0, 0, 0);
        acc = __builtin_amdgcn_mfma_f32_16x16x32_bf16(ha1, b1, acc, 0, 0, 0);
        int col = nt * 16 + p;
        #pragma unroll
        for (int r = 0; r < 4; ++r) {
            int node = node_r + r;
            if (node >= N) continue;
            float v = acc[r];
            if (col < 64) {
                v += bq[col];
                Q[(size_t)node * 64 + col] = (v > 0.f) ? (1.f + v) : __expf(v);
            } else if (col < 128) {
                int c = col - 64;
                v += bk[c];
                float kv = (v > 0.f) ? (1.f + v) : __expf(v);
                K0[(size_t)node * 64 + c] = f32_to_fp8(kv);
            } else {
                int c = col - 128;
                v += bv[c];
                Vh[(size_t)node * 64 + c] = (_Float16)v;
                hidden[(size_t)node * 64 + c] = v * temp[(c >> 4) * 4];  // hop-0 gamma
            }
        }
    }
}

// M layout: per node 64 uint2 (512 fp4 payload), NATURAL columns:
// lane (h*16+p), nibble j holds M[h][d=p][c=j] / scale.  SK[n][lane] = {scale fp8, K fp8}.

// ---------------- epilogue: Q-scale, reduce-scatter over d (natural layout) ----------------
__device__ __forceinline__ void hop_epilogue(
    float* u, float qd, float kacc, float gh,
    float* __restrict__ hidden, int node, int lane)
{
    int p = lane & 15;
    #pragma unroll
    for (int j = 0; j < 16; ++j) u[j] *= qd;
    #pragma unroll
    for (int k = 0; k < 4; ++k) {
        const int m = 1 << k;
        bool bit = (p >> k) & 1;
        const int n = 8 >> k;
        #pragma unroll
        for (int j = 0; j < n; ++j) {
            float give = bit ? u[2 * j]     : u[2 * j + 1];
            float keep = bit ? u[2 * j + 1] : u[2 * j];
            float got  = __shfl_xor(give, m, 64);
            u[j] = keep + got;
        }
    }
    float kq = qd * kacc;
    kq += __shfl_xor(kq, 1, 64);
    kq += __shfl_xor(kq, 2, 64);
    kq += __shfl_xor(kq, 4, 64);
    kq += __shfl_xor(kq, 8, 64);
    float g = gh / (kq + CSTE);
    hidden[(size_t)node * 64 + lane] += g * u[0];
}

// ---------------- hop 1: M1 = A (K ⊗ V) fp4+scale, K1 in SK1 ----------------
__global__ __launch_bounds__(256) void hop1_all(
    const float* __restrict__ Q, const unsigned char* __restrict__ K0,
    const _Float16* __restrict__ Vh,
    const int* __restrict__ offsets, const int* __restrict__ csr,
    const float* __restrict__ temp, const float* __restrict__ hopwise,
    uint2* __restrict__ M1, unsigned short* __restrict__ SK1,
    float* __restrict__ hidden, int N)
{
    int lane = threadIdx.x & 63;
    int node = blockIdx.x * 4 + (threadIdx.x >> 6);
    if (node >= N) return;
    int h = lane >> 4;
    float gh = gamma_for(temp, hopwise, h, 1);
    h2 u16[8];
    #pragma unroll
    for (int j = 0; j < 8; ++j) u16[j] = h2{(_Float16)0.f, (_Float16)0.f};
    float kacc = 0.f;
    int beg = offsets[node], end = offsets[node + 1];
    int t = beg;
    for (; t + 1 < end; t += 2) {
        int s0 = csr[t], s1 = csr[t + 1];
        const uint4* v0p = (const uint4*)(Vh + (size_t)s0 * 64 + h * 16);
        const uint4* v1p = (const uint4*)(Vh + (size_t)s1 * 64 + h * 16);
        uint4 a0 = v0p[0], a1 = v0p[1];
        uint4 b0 = v1p[0], b1 = v1p[1];
        float k0 = fp8_to_f32(K0[(size_t)s0 * 64 + lane]);
        float k1 = fp8_to_f32(K0[(size_t)s1 * 64 + lane]);
        kacc += k0 + k1;
        _Float16 k0h = (_Float16)k0, k1h = (_Float16)k1;
        h2 k02 = {k0h, k0h}, k12 = {k1h, k1h};
        const unsigned int aw[8] = {a0.x, a0.y, a0.z, a0.w, a1.x, a1.y, a1.z, a1.w};
        const unsigned int bw[8] = {b0.x, b0.y, b0.z, b0.w, b1.x, b1.y, b1.z, b1.w};
        #pragma unroll
        for (int j = 0; j < 8; ++j) {
            u16[j] += k02 * __builtin_bit_cast(h2, aw[j]);
            u16[j] += k12 * __builtin_bit_cast(h2, bw[j]);
        }
    }
    for (; t < end; ++t) {
        int s = csr[t];
        const uint4* vp = (const uint4*)(Vh + (size_t)s * 64 + h * 16);
        uint4 a0 = vp[0], a1 = vp[1];
        float kk = fp8_to_f32(K0[(size_t)s * 64 + lane]);
        kacc += kk;
        _Float16 kh = (_Float16)kk;
        h2 k2 = {kh, kh};
        const unsigned int aw[8] = {a0.x, a0.y, a0.z, a0.w, a1.x, a1.y, a1.z, a1.w};
        #pragma unroll
        for (int j = 0; j < 8; ++j)
            u16[j] += k2 * __builtin_bit_cast(h2, aw[j]);
    }
    float u[16];
    #pragma unroll
    for (int j = 0; j < 8; ++j) { u[2 * j] = (float)u16[j].x; u[2 * j + 1] = (float)u16[j].y; }
    store_m_row(M1, SK1, node, lane, u, kacc);
    float qd = Q[(size_t)node * 64 + lane];
    hop_epilogue(u, qd, kacc, gh, hidden, node, lane);
}

// ---------------- hops 2/3: fp4 M + packed {scale,K} gather ----------------
template<bool STORE>
__global__ __launch_bounds__(256) void hop23_all(
    const float* __restrict__ Q, const uint2* __restrict__ Mprev,
    const unsigned short* __restrict__ SKprev,
    const int* __restrict__ offsets, const int* __restrict__ csr,
    const float* __restrict__ temp, const float* __restrict__ hopwise,
    uint2* __restrict__ Mnext, unsigned short* __restrict__ SKnext,
    float* __restrict__ hidden, int N, int hop)
{
    int lane = threadIdx.x & 63;
    int node = blockIdx.x * 4 + (threadIdx.x >> 6);
    if (node >= N) return;
    float gh = gamma_for(temp, hopwise, lane >> 4, hop);
    const uint2* Mb = Mprev + lane;
    const unsigned short* SKb = SKprev + lane;
    float u[16];
    #pragma unroll
    for (int j = 0; j < 16; ++j) u[j] = 0.f;
    float kacc = 0.f;
    int beg = offsets[node], end = offsets[node + 1];
    int t = beg;
    for (; t + 3 < end; t += 4) {
        int s0 = csr[t], s1 = csr[t + 1], s2 = csr[t + 2], s3 = csr[t + 3];
        uint2 w0 = Mb[(size_t)s0 * 64];
        uint2 w1 = Mb[(size_t)s1 * 64];
        uint2 w2 = Mb[(size_t)s2 * 64];
        uint2 w3 = Mb[(size_t)s3 * 64];
        unsigned int q0 = SKb[(size_t)s0 * 64];
        unsigned int q1 = SKb[(size_t)s1 * 64];
        unsigned int q2 = SKb[(size_t)s2 * 64];
        unsigned int q3 = SKb[(size_t)s3 * 64];
        kacc += (fp8_to_f32(q0 >> 8) + fp8_to_f32(q1 >> 8))
              + (fp8_to_f32(q2 >> 8) + fp8_to_f32(q3 >> 8));
        float v[16];
        float s;
        s = fp8_to_f32(q0 & 0xffu); fp4x16_dec(w0, v);
        #pragma unroll
        for (int j = 0; j < 16; ++j) u[j] = fmaf(s, v[j], u[j]);
        s = fp8_to_f32(q1 & 0xffu); fp4x16_dec(w1, v);
        #pragma unroll
        for (int j = 0; j < 16; ++j) u[j] = fmaf(s, v[j], u[j]);
        s = fp8_to_f32(q2 & 0xffu); fp4x16_dec(w2, v);
        #pragma unroll
        for (int j = 0; j < 16; ++j) u[j] = fmaf(s, v[j], u[j]);
        s = fp8_to_f32(q3 & 0xffu); fp4x16_dec(w3, v);
        #pragma unroll
        for (int j = 0; j < 16; ++j) u[j] = fmaf(s, v[j], u[j]);
    }
    for (; t < end; ++t) {
        int sn = csr[t];
        uint2 w = Mb[(size_t)sn * 64];
        unsigned int q = SKb[(size_t)sn * 64];
        kacc += fp8_to_f32(q >> 8);
        float v[16];
        float s = fp8_to_f32(q & 0xffu);
        fp4x16_dec(w, v);
        #pragma unroll
        for (int j = 0; j < 16; ++j) u[j] = fmaf(s, v[j], u[j]);
    }
    if (STORE) store_m_row(Mnext, SKnext, node, lane, u, kacc);
    float qd = Q[(size_t)node * 64 + lane];
    hop_epilogue(u, qd, kacc, gh, hidden, node, lane);
}

// ---------------- output projection ----------------
__global__ __launch_bounds__(256) void out_kernel(
    const float* __restrict__ hidden, const float* __restrict__ Wo,
    const float* __restrict__ bo, float* __restrict__ out, int N)
{
    __shared__ float wo[HID * CC];
    for (int i = threadIdx.x; i < HID * CC; i += 256) wo[i] = Wo[i];
    __syncthreads();
    int idx = blockIdx.x * 256 + threadIdx.x;
    int n = idx >> 4, c = idx & 15;
    if (n >= N) return;
    float acc = bo[c];
    const float4* hp4 = (const float4*)(hidden + (size_t)n * HID);
    #pragma unroll
    for (int j4 = 0; j4 < 16; ++j4) {
        float4 hv = hp4[j4];
        acc += hv.x * wo[(4 * j4 + 0) * CC + c] + hv.y * wo[(4 * j4 + 1) * CC + c]
             + hv.z * wo[(4 * j4 + 2) * CC + c] + hv.w * wo[(4 * j4 + 3) * CC + c];
    }
    out[(size_t)n * CC + c] = acc;
}

extern "C" void kernel_launch(void* const* d_in, const int* in_sizes, int n_in,
                              void* d_out, int out_size, void* d_ws, size_t ws_size,
                              hipStream_t stream) {
    const float* x       = (const float*)d_in[0];
    const int*   ei      = (const int*)  d_in[1];
    const float* Wi      = (const float*)d_in[2];
    const float* bi      = (const float*)d_in[3];
    const float* Wq      = (const float*)d_in[4];
    const float* bq      = (const float*)d_in[5];
    const float* Wk      = (const float*)d_in[6];
    const float* bk      = (const float*)d_in[7];
    const float* Wv      = (const float*)d_in[8];
    const float* bv      = (const float*)d_in[9];
    const float* Wo      = (const float*)d_in[10];
    const float* bo      = (const float*)d_in[11];
    const float* hopwise = (const float*)d_in[12];
    const float* temp    = (const float*)d_in[13];

    const int N = in_sizes[0] / F_IN;
    const int E = in_sizes[1] / 2;

    char* ws = (char*)d_ws;
    size_t off = 0;
    auto take = [&](size_t bytes) -> char* {
        char* p = ws + off;
        off += (bytes + 255) & ~(size_t)255;
        return p;
    };
    float*          Q      = (float*)take((size_t)N * 64 * 4);
    _Float16*       Vh     = (_Float16*)take((size_t)N * 64 * 2);
    float*          hidden = (float*)take((size_t)N * 64 * 4);
    unsigned char*  K0     = (unsigned char*)take((size_t)N * 64);
    unsigned short* SK1    = (unsigned short*)take((size_t)N * 64 * 2);
    unsigned short* SK2    = (unsigned short*)take((size_t)N * 64 * 2);
    int*            degcur = (int*)take((size_t)2 * N * 4);   // deg | cursor
    int*            offs   = (int*)take((size_t)(N + 1) * 4);
    int*            csr    = (int*)take((size_t)E * 4);
    int             nb     = (N + 4095) / 4096;
    int*            bsum   = (int*)take((size_t)nb * 4);
    uint2*          M1     = (uint2*)take((size_t)N * 512);
    uint2*          M2     = (uint2*)take((size_t)N * 512);

    int* deg    = degcur;
    int* cursor = degcur + N;

    hipMemsetAsync(degcur, 0, (size_t)2 * N * 4, stream);

    int eb = (E + 255) / 256;
    count_kernel<<<eb, 256, 0, stream>>>(ei, deg, E);
    scan_a<<<nb, 1024, 0, stream>>>(deg, offs, bsum, N);
    scan_c<<<(N + 255) / 256, 256, 0, stream>>>(offs, bsum, nb, N);
    scatter_kernel<<<eb, 256, 0, stream>>>(ei, offs, cursor, csr, E);

    int qb = (N + 63) / 64;
    qkv_mfma<<<qb, 256, 0, stream>>>(x, Wi, bi, Wq, bq, Wk, bk, Wv, bv,
                                     temp, Q, K0, Vh, hidden, N);

    int nb4 = (N + 3) / 4;
    hop1_all<<<nb4, 256, 0, stream>>>(Q, K0, Vh, offs, csr, temp, hopwise,
                                      M1, SK1, hidden, N);
    hop23_all<true ><<<nb4, 256, 0, stream>>>(Q, M1, SK1, offs, csr, temp, hopwise,
                                              M2, SK2, hidden, N, 2);
    hop23_all<false><<<nb4, 256, 0, stream>>>(Q, M2, SK2, offs, csr, temp, hopwise,
                                              (uint2*)nullptr, (unsigned short*)nullptr,
                                              hidden, N, 3);

    int ob = (N * CC + 255) / 256;
    out_kernel<<<ob, 256, 0, stream>>>(hidden, Wo, bo, (float*)d_out, N);
}